// Round 1
// baseline (3251.759 us; speedup 1.0000x reference)
//
#include <hip/hip_runtime.h>
#include <math.h>

#define CMAX 8
#define KMAX 16
#define TPB 256

struct P {
  const float* fs; const int* ys; const float* fq;
  int S, Q, D, BN, NMAX;
  float* proto;
  float* G;
  float* cosq;
  int* ybt;
  int* cls; int* scount; int* qcount; int* qidx; int* kq;
  float* thr;
  int* rowcnt; int* rowoff; int* paircnt; int* basev;
  int* meta;     // [0]=C [1]=n [2]=k
  int* uv;
  float* rn2;
  int* nbrs; float* dnb; float* wgt; float* sigma;
  int* indeg; int* inoff; int* cursor; int* insrc; float* inw;
  float* amat; float* dinv; float* dmin; float* scalev;
  float* yA; float* yB;
  float* meddenom;
  int* outp;
};

__device__ inline unsigned f2key(float f){
  unsigned b=__float_as_uint(f);
  return (b&0x80000000u)? ~b : (b|0x80000000u);
}
__device__ inline float key2f(unsigned k){
  unsigned b=(k&0x80000000u)? (k^0x80000000u) : ~k;
  return __uint_as_float(b);
}

// ---------- setup: unique classes + support counts ----------
__global__ void k_init(P p){
  if (threadIdx.x==0){
    int labs[CMAX]; int cnt[CMAX]; int C=0;
    for (int s=0;s<p.S;s++){
      int l=p.ys[s]; int f=-1;
      for(int c=0;c<C;c++) if(labs[c]==l){f=c;break;}
      if(f<0){ if(C<CMAX){labs[C]=l;cnt[C]=1;C++;} }
      else cnt[f]++;
    }
    for(int a=0;a<C;a++)for(int b=a+1;b<C;b++)
      if(labs[b]<labs[a]){int t=labs[a];labs[a]=labs[b];labs[b]=t;
                          t=cnt[a];cnt[a]=cnt[b];cnt[b]=t;}
    for(int c=0;c<C;c++){p.cls[c]=labs[c];p.scount[c]=cnt[c];}
    p.meta[0]=C;
  }
}

// ---------- prototypes (mean of support per class) ----------
__global__ void k_proto(P p){
  int c=blockIdx.x; int C=p.meta[0];
  for(int d=threadIdx.x; d<p.D; d+=blockDim.x){
    float s=0.f;
    if(c<C){
      int lab=p.cls[c];
      for(int j=0;j<p.S;j++) if(p.ys[j]==lab) s+=p.fs[(size_t)j*p.D+d];
      s/= (float)p.scount[c];
    }
    p.proto[(size_t)c*p.D+d]=s;
  }
}

// ---------- Gram matrix over B = [feat_q ; prototypes] ----------
__global__ void k_gram(P p){
  __shared__ float arow[640];
  int a=blockIdx.x;
  const float* ra = (a<p.Q)? p.fq + (size_t)a*p.D : p.proto + (size_t)(a-p.Q)*p.D;
  for(int d=threadIdx.x; d<p.D; d+=blockDim.x) arow[d]=ra[d];
  __syncthreads();
  for(int b=threadIdx.x; b<p.BN; b+=blockDim.x){
    const float* rb=(b<p.Q)? p.fq+(size_t)b*p.D : p.proto+(size_t)(b-p.Q)*p.D;
    float s=0.f;
    for(int d=0;d<p.D;d++) s += arow[d]*rb[d];
    p.G[(size_t)a*p.BN+b]=s;
  }
}

// ---------- cosine matrix of queries ----------
__global__ void k_cos(P p){
  int t=blockIdx.x*blockDim.x+threadIdx.x;
  if(t>=p.Q*p.Q)return;
  int i=t/p.Q, j=t%p.Q;
  p.cosq[t]=p.G[(size_t)i*p.BN+j]/(sqrtf(p.G[(size_t)i*p.BN+i])*sqrtf(p.G[(size_t)j*p.BN+j]));
}

// ---------- bootstrap labels ----------
__global__ void k_yboot(P p){
  int q=blockIdx.x*blockDim.x+threadIdx.x;
  if(q>=p.Q)return;
  int C=p.meta[0];
  float gq=p.G[(size_t)q*p.BN+q];
  float best=INFINITY; int bc=0;
  for(int c=0;c<C;c++){
    int pc=p.Q+c;
    float d2=gq+p.G[(size_t)pc*p.BN+pc]-2.f*p.G[(size_t)q*p.BN+pc];
    d2=fmaxf(d2,0.f);
    if(d2<best){best=d2;bc=c;}
  }
  p.ybt[q]=bc;
}

// ---------- per-class index lists + kq ----------
__global__ void k_qidx(P p){
  int c=blockIdx.x; if(threadIdx.x!=0)return;
  int C=p.meta[0];
  if(c>=C){p.qcount[c]=0;p.kq[c]=0;return;}
  int cnt=0;
  for(int q=0;q<p.Q;q++) if(p.ybt[q]==c) p.qidx[c*p.Q+cnt++]=q;
  p.qcount[c]=cnt;
  float best=INFINITY; int bi=0;
  int pc=p.Q+c;
  for(int t=0;t<cnt;t++){
    int q=p.qidx[c*p.Q+t];
    float d2=fmaxf(p.G[(size_t)q*p.BN+q]+p.G[(size_t)pc*p.BN+pc]-2.f*p.G[(size_t)q*p.BN+pc],0.f);
    if(d2<best){best=d2;bi=q;}
  }
  p.kq[c]=bi;
}

// ---------- per-class median of cos submatrix (bit-exact selection) ----------
__global__ void k_median(P p){
  __shared__ unsigned sLo,sHi; __shared__ int scnt[TPB];
  int c=blockIdx.x; int C=p.meta[0];
  int m=(c<C)? p.qcount[c]:0;
  if(m<2){ if(threadIdx.x==0) p.thr[c]=INFINITY; return; }
  int total=m*m; int target=(total-1)/2;
  if(threadIdx.x==0){sLo=0u;sHi=0xFFFFFFFFu;}
  __syncthreads();
  while(true){
    unsigned lo=sLo,hi=sHi;
    if(lo>=hi)break;
    unsigned mid=lo+((hi-lo)>>1);
    int cnt=0;
    for(int a=0;a<m;a++){
      int ia=p.qidx[c*p.Q+a];
      const float* row=p.cosq+(size_t)ia*p.Q;
      for(int b=threadIdx.x;b<m;b+=blockDim.x){
        int ib=p.qidx[c*p.Q+b];
        cnt += (f2key(row[ib])<=mid);
      }
    }
    scnt[threadIdx.x]=cnt; __syncthreads();
    for(int s=blockDim.x/2;s>0;s>>=1){
      if(threadIdx.x<s) scnt[threadIdx.x]+=scnt[threadIdx.x+s];
      __syncthreads();
    }
    if(threadIdx.x==0){ if(scnt[0]>=target+1) sHi=mid; else sLo=mid+1; }
    __syncthreads();
  }
  if(threadIdx.x==0) p.thr[c]=key2f(sLo);
}

// ---------- per-class pair row-counts + prefix ----------
__global__ void k_rowcnt(P p){
  int c=blockIdx.x; int C=p.meta[0];
  int m=(c<C)? p.qcount[c]:0;
  if(m<2){ if(threadIdx.x==0) p.paircnt[c]=0; return; }
  float th=p.thr[c];
  for(int a=threadIdx.x;a<m;a+=blockDim.x){
    int ia=p.qidx[c*p.Q+a]; int cnt=0;
    const float* row=p.cosq+(size_t)ia*p.Q;
    for(int b=a+1;b<m;b++){
      int ib=p.qidx[c*p.Q+b];
      cnt += (row[ib]>=th);
    }
    p.rowcnt[c*p.Q+a]=cnt;
  }
  __syncthreads();
  if(threadIdx.x==0){
    int run=0;
    for(int a=0;a<m;a++){p.rowoff[c*p.Q+a]=run; run+=p.rowcnt[c*p.Q+a];}
    p.paircnt[c]=run;
  }
}

// ---------- bases, n, k ----------
__global__ void k_bases(P p){
  int C=p.meta[0]; int cur=p.Q;
  for(int c=0;c<C;c++){
    p.basev[c]=cur;
    if(p.qcount[c]>=2) cur += p.paircnt[c]+1;
  }
  int n=cur; if(n>p.NMAX)n=p.NMAX;
  p.meta[1]=n;
  int k=31-__clz(n); if(k<1)k=1; if(k>KMAX-1)k=KMAX-1;
  p.meta[2]=k;
}

// ---------- uv for query rows + zero indeg ----------
__global__ void k_uv(P p){
  int r=blockIdx.x*blockDim.x+threadIdx.x;
  if(r>=p.NMAX)return;
  p.indeg[r]=0;
  if(r<p.Q){ p.uv[2*r]=r; p.uv[2*r+1]=r; }
}

// ---------- uv for virtual rows ----------
__global__ void k_uvpairs(P p){
  int c=blockIdx.x; int C=p.meta[0];
  int m=(c<C)? p.qcount[c]:0;
  if(m<2)return;
  float th=p.thr[c];
  int bs=p.basev[c];
  for(int a=threadIdx.x;a<m;a+=blockDim.x){
    int ia=p.qidx[c*p.Q+a];
    int off=bs+p.rowoff[c*p.Q+a]; int cnt=0;
    const float* row=p.cosq+(size_t)ia*p.Q;
    for(int b=a+1;b<m;b++){
      int ib=p.qidx[c*p.Q+b];
      if(row[ib]>=th){
        int r=off+cnt;
        p.uv[2*r]=ia; p.uv[2*r+1]=ib;
        cnt++;
      }
    }
  }
  if(threadIdx.x==0){
    int r=bs+p.paircnt[c];
    p.uv[2*r]=p.Q+c; p.uv[2*r+1]=p.kq[c];
  }
}

// ---------- per-row norm^2 from Gram ----------
__global__ void k_rn2(P p){
  int r=blockIdx.x*blockDim.x+threadIdx.x;
  int n=p.meta[1]; if(r>=n)return;
  int u=p.uv[2*r],v=p.uv[2*r+1];
  p.rn2[r]=0.25f*(p.G[(size_t)u*p.BN+u]+2.f*p.G[(size_t)u*p.BN+v]+p.G[(size_t)v*p.BN+v]);
}

// ---------- kNN: top-(k+1) smallest distances per row ----------
__global__ void k_knn(P p){
  __shared__ float sD[TPB]; __shared__ int sJ[TPB]; __shared__ int sT[TPB];
  int i=blockIdx.x;
  int n=p.meta[1]; if(i>=n)return;
  int k=p.meta[2]; int kp1=k+1;
  int tid=threadIdx.x;
  int u1=p.uv[2*i],v1=p.uv[2*i+1];
  float rni=p.rn2[i];
  const float* Gu=p.G+(size_t)u1*p.BN;
  const float* Gv=p.G+(size_t)v1*p.BN;
  float ld[KMAX]; int li[KMAX]; int cnt=0;
  for(int j=tid;j<n;j+=TPB){
    int u2=p.uv[2*j],v2=p.uv[2*j+1];
    float dot=0.25f*(Gu[u2]+Gu[v2]+Gv[u2]+Gv[v2]);
    float d2=rni+p.rn2[j]-2.f*dot;
    d2=fmaxf(d2,0.f);
    bool take;
    if(cnt<kp1) take=true;
    else {
      float wv=ld[cnt-1];
      take=(d2<wv)||(d2==wv && j<li[cnt-1]);
    }
    if(take){
      int pos=(cnt<kp1)?cnt:(kp1-1);
      while(pos>0 && (d2<ld[pos-1] || (d2==ld[pos-1] && j<li[pos-1]))){
        ld[pos]=ld[pos-1]; li[pos]=li[pos-1]; pos--;
      }
      ld[pos]=d2; li[pos]=j;
      if(cnt<kp1)cnt++;
    }
  }
  int pos=0;
  for(int t=0;t<kp1;t++){
    sD[tid]=(pos<cnt)? ld[pos]:INFINITY;
    sJ[tid]=(pos<cnt)? li[pos]:0x7FFFFFFF;
    sT[tid]=tid;
    __syncthreads();
    for(int s=TPB/2;s>0;s>>=1){
      if(tid<s){
        float dA=sD[tid],dB=sD[tid+s];
        if(dB<dA || (dB==dA && sJ[tid+s]<sJ[tid])){
          sD[tid]=dB;sJ[tid]=sJ[tid+s];sT[tid]=sT[tid+s];
        }
      }
      __syncthreads();
    }
    if(tid==sT[0]) pos++;
    if(tid==0){
      if(t>=1){
        p.nbrs[(size_t)i*KMAX+t-1]=sJ[0];
        p.dnb[(size_t)i*KMAX+t-1]=sqrtf(fmaxf(sD[0],1e-30f));
      }
      if(t==kp1-1) p.sigma[i]=sqrtf(fmaxf(sD[0],1e-30f))+1e-8f;
    }
    __syncthreads();
  }
}

// ---------- edge weights ----------
__global__ void k_wgt(P p){
  int i=blockIdx.x*blockDim.x+threadIdx.x;
  int n=p.meta[1]; if(i>=n)return;
  int k=p.meta[2];
  float si=p.sigma[i];
  for(int q=0;q<k;q++){
    int j=p.nbrs[(size_t)i*KMAX+q];
    p.wgt[(size_t)i*KMAX+q]=expf(-p.dnb[(size_t)i*KMAX+q]/(si*p.sigma[j]));
  }
}

// ---------- in-degree count ----------
__global__ void k_count(P p){
  int i=blockIdx.x*blockDim.x+threadIdx.x;
  int n=p.meta[1]; if(i>=n)return;
  int k=p.meta[2];
  for(int q=0;q<k;q++) atomicAdd(&p.indeg[p.nbrs[(size_t)i*KMAX+q]],1);
}

// ---------- exclusive scan of indeg ----------
__global__ void k_scan(P p){
  __shared__ int part[TPB];
  int n=p.meta[1];
  int chunk=(n+TPB-1)/TPB;
  int beg=threadIdx.x*chunk, end=beg+chunk; if(end>n)end=n;
  int s=0;
  for(int i=beg;i<end;i++) s+=p.indeg[i];
  part[threadIdx.x]=s; __syncthreads();
  if(threadIdx.x==0){
    int run=0;
    for(int t=0;t<TPB;t++){int v=part[t];part[t]=run;run+=v;}
    p.inoff[n]=run;
  }
  __syncthreads();
  int run=part[threadIdx.x];
  for(int i=beg;i<end;i++){
    p.inoff[i]=run; p.cursor[i]=run; run+=p.indeg[i];
  }
}

// ---------- fill transpose edges ----------
__global__ void k_fill(P p){
  int i=blockIdx.x*blockDim.x+threadIdx.x;
  int n=p.meta[1]; if(i>=n)return;
  int k=p.meta[2];
  for(int q=0;q<k;q++){
    int dst=p.nbrs[(size_t)i*KMAX+q];
    int slot=atomicAdd(&p.cursor[dst],1);
    p.insrc[slot]=i; p.inw[slot]=p.wgt[(size_t)i*KMAX+q];
  }
}

// ---------- sort each in-edge row by source (determinism) ----------
__global__ void k_sortin(P p){
  int i=blockIdx.x*blockDim.x+threadIdx.x;
  int n=p.meta[1]; if(i>=n)return;
  int b=p.inoff[i], e=p.inoff[i+1];
  for(int x=b+1;x<e;x++){
    int s=p.insrc[x]; float w=p.inw[x]; int y=x-1;
    while(y>=b && p.insrc[y]>s){
      p.insrc[y+1]=p.insrc[y]; p.inw[y+1]=p.inw[y]; y--;
    }
    p.insrc[y+1]=s; p.inw[y+1]=w;
  }
}

// ---------- D_inv, a-matrix, d_min ----------
__global__ void k_dad(P p){
  int i=blockIdx.x*blockDim.x+threadIdx.x;
  int n=p.meta[1]; if(i>=n)return;
  int k=p.meta[2]; int C=p.meta[0];
  float s=0.f;
  for(int q=0;q<k;q++) s+=p.wgt[(size_t)i*KMAX+q];
  for(int e=p.inoff[i];e<p.inoff[i+1];e++) s+=p.inw[e];
  p.dinv[i]=1.f/(0.5f*s+1e-8f);
  int u=p.uv[2*i],v=p.uv[2*i+1];
  float rn=p.rn2[i]; float mn=INFINITY;
  #pragma unroll
  for(int c=0;c<CMAX;c++){
    if(c<C){
      int pc=p.Q+c;
      float a=rn+p.G[(size_t)pc*p.BN+pc]-(p.G[(size_t)u*p.BN+pc]+p.G[(size_t)v*p.BN+pc]);
      a=fmaxf(a,0.f);
      p.amat[(size_t)i*CMAX+c]=a;
      mn=fminf(mn,a);
    }
  }
  p.dmin[i]=sqrtf(fmaxf(mn,1e-30f));
}

// ---------- median of d (bit-exact) ----------
__global__ void k_medd(P p){
  __shared__ unsigned sLo,sHi; __shared__ int scnt[TPB];
  int n=p.meta[1];
  int target=(n-1)/2;
  if(threadIdx.x==0){sLo=0u;sHi=0xFFFFFFFFu;}
  __syncthreads();
  while(true){
    unsigned lo=sLo,hi=sHi;
    if(lo>=hi)break;
    unsigned mid=lo+((hi-lo)>>1);
    int cnt=0;
    for(int i=threadIdx.x;i<n;i+=blockDim.x) cnt += (f2key(p.dmin[i])<=mid);
    scnt[threadIdx.x]=cnt; __syncthreads();
    for(int s=blockDim.x/2;s>0;s>>=1){
      if(threadIdx.x<s) scnt[threadIdx.x]+=scnt[threadIdx.x+s];
      __syncthreads();
    }
    if(threadIdx.x==0){ if(scnt[0]>=target+1) sHi=mid; else sLo=mid+1; }
    __syncthreads();
  }
  if(threadIdx.x==0){
    float med=key2f(sLo);
    p.meddenom[0]=2.f*med*med+1e-8f;
  }
}

// ---------- lambda, scale, y0 ----------
__global__ void k_y0(P p){
  int i=blockIdx.x*blockDim.x+threadIdx.x;
  int n=p.meta[1]; if(i>=n)return;
  int C=p.meta[0];
  float la=expf(-(p.dmin[i]*p.dmin[i])/p.meddenom[0]);
  p.scalev[i]=la*p.dinv[i];
  float mn=INFINITY;
  #pragma unroll
  for(int c=0;c<CMAX;c++) if(c<C) mn=fminf(mn,p.amat[(size_t)i*CMAX+c]);
  float ex[CMAX]; float sum=0.f;
  #pragma unroll
  for(int c=0;c<CMAX;c++){
    float e=(c<C)? expf(mn-p.amat[(size_t)i*CMAX+c]) : 0.f;
    ex[c]=e; sum+=e;
  }
  float inv=1.f/sum;
  #pragma unroll
  for(int c=0;c<CMAX;c++) if(c<C) p.yA[(size_t)i*CMAX+c]=ex[c]*inv;
}

// ---------- fused 50-iteration label propagation + argmax ----------
__global__ void __launch_bounds__(1024) k_iter(P p){
  __shared__ float sred[1024];
  int n=p.meta[1]; int k=p.meta[2]; int C=p.meta[0];
  float* cur=p.yA; float* nxt=p.yB;
  int tid=threadIdx.x;
  for(int t=0;t<50;t++){
    float dmx=0.f;
    for(int i=tid;i<n;i+=blockDim.x){
      float wy[CMAX];
      #pragma unroll
      for(int c=0;c<CMAX;c++) wy[c]=0.f;
      for(int q=0;q<k;q++){
        int j=p.nbrs[(size_t)i*KMAX+q];
        float w=p.wgt[(size_t)i*KMAX+q];
        const float* yr=cur+(size_t)j*CMAX;
        #pragma unroll
        for(int c=0;c<CMAX;c++) if(c<C) wy[c]+=w*yr[c];
      }
      int e0=p.inoff[i],e1=p.inoff[i+1];
      for(int e=e0;e<e1;e++){
        int j=p.insrc[e]; float w=p.inw[e];
        const float* yr=cur+(size_t)j*CMAX;
        #pragma unroll
        for(int c=0;c<CMAX;c++) if(c<C) wy[c]+=w*yr[c];
      }
      float sc=p.scalev[i]*0.5f;
      float lg[CMAX]; float mx=-INFINITY;
      #pragma unroll
      for(int c=0;c<CMAX;c++){
        if(c<C){
          float l=-p.amat[(size_t)i*CMAX+c]+sc*wy[c];
          lg[c]=l; mx=fmaxf(mx,l);
        }
      }
      float sum=0.f;
      #pragma unroll
      for(int c=0;c<CMAX;c++){
        if(c<C){ float e=expf(lg[c]-mx); lg[c]=e; sum+=e; }
      }
      float inv=1.f/sum;
      #pragma unroll
      for(int c=0;c<CMAX;c++){
        if(c<C){
          float yn=lg[c]*inv;
          nxt[(size_t)i*CMAX+c]=yn;
          dmx=fmaxf(dmx,fabsf(yn-cur[(size_t)i*CMAX+c]));
        }
      }
    }
    sred[tid]=dmx; __syncthreads();
    for(int s=blockDim.x/2;s>0;s>>=1){
      if(tid<s) sred[tid]=fmaxf(sred[tid],sred[tid+s]);
      __syncthreads();
    }
    if(sred[0]<1e-4f) break;     // frozen from here on (matches reference)
    float* tmp=cur;cur=nxt;nxt=tmp;
    __syncthreads();
  }
  __syncthreads();
  for(int q=tid;q<p.Q;q+=blockDim.x){
    float best=cur[(size_t)q*CMAX+0]; int bc=0;
    for(int c=1;c<C;c++){
      float v=cur[(size_t)q*CMAX+c];
      if(v>best){best=v;bc=c;}
    }
    p.outp[q]=bc;
  }
}

// =======================================================================

static void make_layout(char* base,int S,int Q,int D,int BN,long N,
                        const float*fs,const int*ys,const float*fq,
                        int* outp, P* pp, size_t* need){
  size_t off=0;
  auto A=[&](size_t b)->char*{
    size_t o=(off+255)&~(size_t)255; off=o+b; return base+o;
  };
  P p{};
  p.fs=fs;p.ys=ys;p.fq=fq;p.S=S;p.Q=Q;p.D=D;p.BN=BN;p.NMAX=(int)N;
  p.proto=(float*)A(4ul*CMAX*D);
  p.G=(float*)A(4ul*(size_t)BN*BN);
  p.cosq=(float*)A(4ul*(size_t)Q*Q);
  p.ybt=(int*)A(4ul*Q);
  p.cls=(int*)A(4ul*CMAX);
  p.scount=(int*)A(4ul*CMAX);
  p.qcount=(int*)A(4ul*CMAX);
  p.qidx=(int*)A(4ul*CMAX*Q);
  p.kq=(int*)A(4ul*CMAX);
  p.thr=(float*)A(4ul*CMAX);
  p.rowcnt=(int*)A(4ul*CMAX*Q);
  p.rowoff=(int*)A(4ul*CMAX*Q);
  p.paircnt=(int*)A(4ul*CMAX);
  p.basev=(int*)A(4ul*CMAX);
  p.meta=(int*)A(4ul*16);
  p.uv=(int*)A(8ul*N);
  p.rn2=(float*)A(4ul*N);
  p.nbrs=(int*)A(4ul*KMAX*N);
  p.dnb=(float*)A(4ul*KMAX*N);
  p.wgt=(float*)A(4ul*KMAX*N);
  p.sigma=(float*)A(4ul*N);
  p.indeg=(int*)A(4ul*N);
  p.inoff=(int*)A(4ul*(N+1));
  p.cursor=(int*)A(4ul*N);
  p.insrc=(int*)A(4ul*KMAX*N);
  p.inw=(float*)A(4ul*KMAX*N);
  p.amat=(float*)A(4ul*CMAX*N);
  p.dinv=(float*)A(4ul*N);
  p.dmin=(float*)A(4ul*N);
  p.scalev=(float*)A(4ul*N);
  p.yA=(float*)A(4ul*CMAX*N);
  p.yB=(float*)A(4ul*CMAX*N);
  p.meddenom=(float*)A(4ul*4);
  p.outp=outp;
  *pp=p; *need=off;
}

extern "C" void kernel_launch(void* const* d_in, const int* in_sizes, int n_in,
                              void* d_out, int out_size, void* d_ws, size_t ws_size,
                              hipStream_t stream){
  const float* fs=(const float*)d_in[0];
  const int*   ys=(const int*)d_in[1];
  const float* fq=(const float*)d_in[2];
  int S=in_sizes[1];
  int D=in_sizes[0]/S;
  int Q=in_sizes[2]/D;
  int BN=Q+CMAX;

  long full=(long)Q + (long)Q*(Q-1)/2 + CMAX;   // absolute worst-case n
  long cand[4]={full,16384,8192,5000};
  P p{}; size_t need=0; int NMAX=(int)cand[3];
  for(int ci=0;ci<4;ci++){
    long N=cand[ci]; if(N<Q+CMAX)N=Q+CMAX;
    make_layout((char*)d_ws,S,Q,D,BN,N,fs,ys,fq,(int*)d_out,&p,&need);
    NMAX=(int)N;
    if(need<=ws_size) break;
  }

  int gN=(NMAX+TPB-1)/TPB;

  k_init   <<<1, 64, 0, stream>>>(p);
  k_proto  <<<CMAX, TPB, 0, stream>>>(p);
  k_gram   <<<BN, TPB, 0, stream>>>(p);
  k_cos    <<<(Q*Q+TPB-1)/TPB, TPB, 0, stream>>>(p);
  k_yboot  <<<(Q+TPB-1)/TPB, TPB, 0, stream>>>(p);
  k_qidx   <<<CMAX, 64, 0, stream>>>(p);
  k_median <<<CMAX, TPB, 0, stream>>>(p);
  k_rowcnt <<<CMAX, TPB, 0, stream>>>(p);
  k_bases  <<<1, 1, 0, stream>>>(p);
  k_uv     <<<gN, TPB, 0, stream>>>(p);
  k_uvpairs<<<CMAX, TPB, 0, stream>>>(p);
  k_rn2    <<<gN, TPB, 0, stream>>>(p);
  k_knn    <<<NMAX, TPB, 0, stream>>>(p);
  k_wgt    <<<gN, TPB, 0, stream>>>(p);
  k_count  <<<gN, TPB, 0, stream>>>(p);
  k_scan   <<<1, TPB, 0, stream>>>(p);
  k_fill   <<<gN, TPB, 0, stream>>>(p);
  k_sortin <<<gN, TPB, 0, stream>>>(p);
  k_dad    <<<gN, TPB, 0, stream>>>(p);
  k_medd   <<<1, TPB, 0, stream>>>(p);
  k_y0     <<<gN, TPB, 0, stream>>>(p);
  k_iter   <<<1, 1024, 0, stream>>>(p);
}

// Round 3
// 1757.002 us; speedup vs baseline: 1.8507x; 1.8507x over previous
//
#include <hip/hip_runtime.h>
#include <math.h>

#define CMAX 8
#define KMAX 16
#define TPB 256
#define BNMAX 512

struct P {
  const float* fs; const int* ys; const float* fq;
  int S, Q, D, BN, NMAX;
  float* proto;
  float* G;
  float* cosq;
  int* ybt;
  int* cls; int* scount; int* qcount; int* qidx; int* kq;
  float* thr;
  int* rowcnt; int* rowoff; int* paircnt; int* basev;
  int* meta;     // [0]=C [1]=n [2]=k
  int* uv;
  float* rn2;
  int* nbrs; float* dnb; float* wgt; float* sigma;
  int* indeg; int* inoff; int* cursor;
  int* insrcU; float* inwU; int* indst;   // unsorted transpose edges
  int* insrc; float* inw;                 // rank-sorted transpose edges
  float* amat; float* dinv; float* dmin; float* scalev;
  float* yA; float* yB;
  float* meddenom;
  int* outp;
};

__device__ inline unsigned f2key(float f){
  unsigned b=__float_as_uint(f);
  return (b&0x80000000u)? ~b : (b|0x80000000u);
}
__device__ inline float key2f(unsigned k){
  unsigned b=(k&0x80000000u)? (k^0x80000000u) : ~k;
  return __uint_as_float(b);
}
__device__ inline unsigned long long shfl_xor_u64(unsigned long long v,int m){
  unsigned lo=(unsigned)v, hi=(unsigned)(v>>32);
  lo=__shfl_xor(lo,m,64); hi=__shfl_xor(hi,m,64);
  return (((unsigned long long)hi)<<32)|lo;
}

// ---------- setup: unique classes + support counts ----------
__global__ void k_init(P p){
  if (threadIdx.x==0){
    int labs[CMAX]; int cnt[CMAX]; int C=0;
    for (int s=0;s<p.S;s++){
      int l=p.ys[s]; int f=-1;
      for(int c=0;c<C;c++) if(labs[c]==l){f=c;break;}
      if(f<0){ if(C<CMAX){labs[C]=l;cnt[C]=1;C++;} }
      else cnt[f]++;
    }
    for(int a=0;a<C;a++)for(int b=a+1;b<C;b++)
      if(labs[b]<labs[a]){int t=labs[a];labs[a]=labs[b];labs[b]=t;
                          t=cnt[a];cnt[a]=cnt[b];cnt[b]=t;}
    for(int c=0;c<C;c++){p.cls[c]=labs[c];p.scount[c]=cnt[c];}
    p.meta[0]=C;
  }
}

// ---------- prototypes ----------
__global__ void k_proto(P p){
  int c=blockIdx.x; int C=p.meta[0];
  for(int d=threadIdx.x; d<p.D; d+=blockDim.x){
    float s=0.f;
    if(c<C){
      int lab=p.cls[c];
      for(int j=0;j<p.S;j++) if(p.ys[j]==lab) s+=p.fs[(size_t)j*p.D+d];
      s/= (float)p.scount[c];
    }
    p.proto[(size_t)c*p.D+d]=s;
  }
}

// ---------- Gram matrix over B = [feat_q ; prototypes], float4 inner ----------
__global__ void k_gram(P p){
  __shared__ float arow[1024];
  int a=blockIdx.x;
  const float* ra = (a<p.Q)? p.fq + (size_t)a*p.D : p.proto + (size_t)(a-p.Q)*p.D;
  const float* A = ra;
  if(p.D<=1024){
    for(int d=threadIdx.x; d<p.D; d+=blockDim.x) arow[d]=ra[d];
    __syncthreads();
    A=(const float*)arow;
  }
  int D4=p.D>>2; int Dt=D4<<2;
  for(int b=threadIdx.x; b<p.BN; b+=blockDim.x){
    const float* rb=(b<p.Q)? p.fq+(size_t)b*p.D : p.proto+(size_t)(b-p.Q)*p.D;
    const float4* a4=(const float4*)A;
    const float4* b4=(const float4*)rb;
    float s=0.f;
    #pragma unroll 4
    for(int d=0;d<D4;d++){
      float4 x=a4[d], y=b4[d];
      s += x.x*y.x + x.y*y.y + x.z*y.z + x.w*y.w;
    }
    for(int d=Dt;d<p.D;d++) s += A[d]*rb[d];
    p.G[(size_t)a*p.BN+b]=s;
  }
}

// ---------- cosine matrix of queries ----------
__global__ void k_cos(P p){
  int t=blockIdx.x*blockDim.x+threadIdx.x;
  if(t>=p.Q*p.Q)return;
  int i=t/p.Q, j=t%p.Q;
  p.cosq[t]=p.G[(size_t)i*p.BN+j]/(sqrtf(p.G[(size_t)i*p.BN+i])*sqrtf(p.G[(size_t)j*p.BN+j]));
}

// ---------- bootstrap labels ----------
__global__ void k_yboot(P p){
  int q=blockIdx.x*blockDim.x+threadIdx.x;
  if(q>=p.Q)return;
  int C=p.meta[0];
  float gq=p.G[(size_t)q*p.BN+q];
  float best=INFINITY; int bc=0;
  for(int c=0;c<C;c++){
    int pc=p.Q+c;
    float d2=gq+p.G[(size_t)pc*p.BN+pc]-2.f*p.G[(size_t)q*p.BN+pc];
    d2=fmaxf(d2,0.f);
    if(d2<best){best=d2;bc=c;}
  }
  p.ybt[q]=bc;
}

// ---------- per-class index lists + kq ----------
__global__ void k_qidx(P p){
  int c=blockIdx.x; if(threadIdx.x!=0)return;
  int C=p.meta[0];
  if(c>=C){p.qcount[c]=0;p.kq[c]=0;return;}
  int cnt=0;
  for(int q=0;q<p.Q;q++) if(p.ybt[q]==c) p.qidx[c*p.Q+cnt++]=q;
  p.qcount[c]=cnt;
  float best=INFINITY; int bi=0;
  int pc=p.Q+c;
  for(int t=0;t<cnt;t++){
    int q=p.qidx[c*p.Q+t];
    float d2=fmaxf(p.G[(size_t)q*p.BN+q]+p.G[(size_t)pc*p.BN+pc]-2.f*p.G[(size_t)q*p.BN+pc],0.f);
    if(d2<best){best=d2;bi=q;}
  }
  p.kq[c]=bi;
}

// ---------- per-class median of cos submatrix (bit-exact selection) ----------
__global__ void k_median(P p){
  __shared__ unsigned sLo,sHi; __shared__ int scnt[TPB];
  int c=blockIdx.x; int C=p.meta[0];
  int m=(c<C)? p.qcount[c]:0;
  if(m<2){ if(threadIdx.x==0) p.thr[c]=INFINITY; return; }
  int total=m*m; int target=(total-1)/2;
  if(threadIdx.x==0){sLo=0u;sHi=0xFFFFFFFFu;}
  __syncthreads();
  while(true){
    unsigned lo=sLo,hi=sHi;
    if(lo>=hi)break;
    unsigned mid=lo+((hi-lo)>>1);
    int cnt=0;
    for(int a=0;a<m;a++){
      int ia=p.qidx[c*p.Q+a];
      const float* row=p.cosq+(size_t)ia*p.Q;
      for(int b=threadIdx.x;b<m;b+=blockDim.x){
        int ib=p.qidx[c*p.Q+b];
        cnt += (f2key(row[ib])<=mid);
      }
    }
    scnt[threadIdx.x]=cnt; __syncthreads();
    for(int s=blockDim.x/2;s>0;s>>=1){
      if(threadIdx.x<s) scnt[threadIdx.x]+=scnt[threadIdx.x+s];
      __syncthreads();
    }
    if(threadIdx.x==0){ if(scnt[0]>=target+1) sHi=mid; else sLo=mid+1; }
    __syncthreads();
  }
  if(threadIdx.x==0) p.thr[c]=key2f(sLo);
}

// ---------- per-class pair row-counts + prefix ----------
__global__ void k_rowcnt(P p){
  int c=blockIdx.x; int C=p.meta[0];
  int m=(c<C)? p.qcount[c]:0;
  if(m<2){ if(threadIdx.x==0) p.paircnt[c]=0; return; }
  float th=p.thr[c];
  for(int a=threadIdx.x;a<m;a+=blockDim.x){
    int ia=p.qidx[c*p.Q+a]; int cnt=0;
    const float* row=p.cosq+(size_t)ia*p.Q;
    for(int b=a+1;b<m;b++){
      int ib=p.qidx[c*p.Q+b];
      cnt += (row[ib]>=th);
    }
    p.rowcnt[c*p.Q+a]=cnt;
  }
  __syncthreads();
  if(threadIdx.x==0){
    int run=0;
    for(int a=0;a<m;a++){p.rowoff[c*p.Q+a]=run; run+=p.rowcnt[c*p.Q+a];}
    p.paircnt[c]=run;
  }
}

// ---------- bases, n, k ----------
__global__ void k_bases(P p){
  int C=p.meta[0]; int cur=p.Q;
  for(int c=0;c<C;c++){
    p.basev[c]=cur;
    if(p.qcount[c]>=2) cur += p.paircnt[c]+1;
  }
  int n=cur; if(n>p.NMAX)n=p.NMAX;
  p.meta[1]=n;
  int k=31-__clz(n); if(k<1)k=1; if(k>KMAX-1)k=KMAX-1;
  p.meta[2]=k;
}

// ---------- uv for query rows + zero indeg ----------
__global__ void k_uv(P p){
  int r=blockIdx.x*blockDim.x+threadIdx.x;
  if(r>=p.NMAX)return;
  p.indeg[r]=0;
  if(r<p.Q){ p.uv[2*r]=r; p.uv[2*r+1]=r; }
}

// ---------- uv for virtual rows ----------
__global__ void k_uvpairs(P p){
  int c=blockIdx.x; int C=p.meta[0];
  int m=(c<C)? p.qcount[c]:0;
  if(m<2)return;
  float th=p.thr[c];
  int bs=p.basev[c];
  for(int a=threadIdx.x;a<m;a+=blockDim.x){
    int ia=p.qidx[c*p.Q+a];
    int off=bs+p.rowoff[c*p.Q+a]; int cnt=0;
    const float* row=p.cosq+(size_t)ia*p.Q;
    for(int b=a+1;b<m;b++){
      int ib=p.qidx[c*p.Q+b];
      if(row[ib]>=th){
        int r=off+cnt;
        p.uv[2*r]=ia; p.uv[2*r+1]=ib;
        cnt++;
      }
    }
  }
  if(threadIdx.x==0){
    int r=bs+p.paircnt[c];
    p.uv[2*r]=p.Q+c; p.uv[2*r+1]=p.kq[c];
  }
}

// ---------- per-row norm^2 from Gram ----------
__global__ void k_rn2(P p){
  int r=blockIdx.x*blockDim.x+threadIdx.x;
  int n=p.meta[1]; if(r>=n)return;
  int u=p.uv[2*r],v=p.uv[2*r+1];
  p.rn2[r]=0.25f*(p.G[(size_t)u*p.BN+u]+2.f*p.G[(size_t)u*p.BN+v]+p.G[(size_t)v*p.BN+v]);
}

// ---------- kNN: 1 wave per row, register top-16 via u64 keys ----------
__global__ void k_knn(P p){
  __shared__ float sGu[BNMAX];
  __shared__ float sGv[BNMAX];
  int i=blockIdx.x;
  int n=p.meta[1]; if(i>=n)return;
  int kp1=p.meta[2]+1;
  int lane=threadIdx.x;
  int u1=p.uv[2*i], v1=p.uv[2*i+1];
  const float* Gu=p.G+(size_t)u1*p.BN;
  const float* Gv=p.G+(size_t)v1*p.BN;
  const float* bu=Gu; const float* bv=Gv;
  if(p.BN<=BNMAX){
    for(int d=lane; d<p.BN; d+=64){ sGu[d]=Gu[d]; sGv[d]=Gv[d]; }
    __syncthreads();
    bu=(const float*)sGu; bv=(const float*)sGv;
  }
  float rni=p.rn2[i];
  unsigned long long r[16];
  #pragma unroll
  for(int t=0;t<16;t++) r[t]=0xFFFFFFFFFFFFFFFFull;
  for(int j=lane;j<n;j+=64){
    int2 w=((const int2*)p.uv)[j];
    float dot=0.25f*(bu[w.x]+bu[w.y]+bv[w.x]+bv[w.y]);
    float d2=fmaxf(rni+p.rn2[j]-2.f*dot,0.f);
    unsigned long long key=(((unsigned long long)f2key(d2))<<32)|(unsigned)j;
    if(key<r[15]){
      #pragma unroll
      for(int t=0;t<16;t++){
        unsigned long long lo=key<r[t]?key:r[t];
        unsigned long long hi=key<r[t]?r[t]:key;
        r[t]=lo; key=hi;
      }
    }
  }
  for(int t=0;t<kp1;t++){
    unsigned long long m=r[0];
    #pragma unroll
    for(int s=32;s>=1;s>>=1){
      unsigned long long o=shfl_xor_u64(m,s);
      if(o<m)m=o;
    }
    if(r[0]==m){            // unique keys -> exactly one lane pops
      #pragma unroll
      for(int q=0;q<15;q++) r[q]=r[q+1];
      r[15]=0xFFFFFFFFFFFFFFFFull;
    }
    if(lane==0){
      int j=(int)(unsigned)(m&0xFFFFFFFFull);
      float d2=key2f((unsigned)(m>>32));
      float dd=sqrtf(fmaxf(d2,1e-30f));
      if(t>=1){ p.nbrs[(size_t)i*KMAX+t-1]=j; p.dnb[(size_t)i*KMAX+t-1]=dd; }
      if(t==kp1-1) p.sigma[i]=dd+1e-8f;
    }
  }
}

// ---------- edge weights ----------
__global__ void k_wgt(P p){
  int i=blockIdx.x*blockDim.x+threadIdx.x;
  int n=p.meta[1]; if(i>=n)return;
  int k=p.meta[2];
  float si=p.sigma[i];
  for(int q=0;q<k;q++){
    int j=p.nbrs[(size_t)i*KMAX+q];
    p.wgt[(size_t)i*KMAX+q]=expf(-p.dnb[(size_t)i*KMAX+q]/(si*p.sigma[j]));
  }
}

// ---------- in-degree count ----------
__global__ void k_count(P p){
  int i=blockIdx.x*blockDim.x+threadIdx.x;
  int n=p.meta[1]; if(i>=n)return;
  int k=p.meta[2];
  for(int q=0;q<k;q++) atomicAdd(&p.indeg[p.nbrs[(size_t)i*KMAX+q]],1);
}

// ---------- exclusive scan of indeg ----------
__global__ void k_scan(P p){
  __shared__ int part[TPB];
  int n=p.meta[1];
  int chunk=(n+TPB-1)/TPB;
  int beg=threadIdx.x*chunk, end=beg+chunk; if(end>n)end=n;
  int s=0;
  for(int i=beg;i<end;i++) s+=p.indeg[i];
  part[threadIdx.x]=s; __syncthreads();
  if(threadIdx.x==0){
    int run=0;
    for(int t=0;t<TPB;t++){int v=part[t];part[t]=run;run+=v;}
    p.inoff[n]=run;
  }
  __syncthreads();
  int run=part[threadIdx.x];
  for(int i=beg;i<end;i++){
    p.inoff[i]=run; p.cursor[i]=run; run+=p.indeg[i];
  }
}

// ---------- fill transpose edges (unsorted, atomic slots) ----------
__global__ void k_fill(P p){
  int i=blockIdx.x*blockDim.x+threadIdx.x;
  int n=p.meta[1]; if(i>=n)return;
  int k=p.meta[2];
  for(int q=0;q<k;q++){
    int dst=p.nbrs[(size_t)i*KMAX+q];
    int slot=atomicAdd(&p.cursor[dst],1);
    p.insrcU[slot]=i; p.inwU[slot]=p.wgt[(size_t)i*KMAX+q]; p.indst[slot]=dst;
  }
}

// ---------- deterministic order: thread-per-edge rank-by-count ----------
__global__ void k_rank(P p){
  int e=blockIdx.x*blockDim.x+threadIdx.x;
  int n=p.meta[1];
  int E=p.inoff[n];
  if(e>=E)return;
  int dst=p.indst[e];
  int b=p.inoff[dst], en=p.inoff[dst+1];
  int s=p.insrcU[e]; float w=p.inwU[e];
  int rank=0;
  for(int x=b;x<en;x++) rank += (p.insrcU[x]<s);
  p.insrc[b+rank]=s; p.inw[b+rank]=w;
}

// ---------- D_inv, a-matrix (+INF padding), d_min ----------
__global__ void k_dad(P p){
  int i=blockIdx.x*blockDim.x+threadIdx.x;
  int n=p.meta[1]; if(i>=n)return;
  int k=p.meta[2]; int C=p.meta[0];
  float s=0.f;
  for(int q=0;q<k;q++) s+=p.wgt[(size_t)i*KMAX+q];
  for(int e=p.inoff[i];e<p.inoff[i+1];e++) s+=p.inw[e];
  p.dinv[i]=1.f/(0.5f*s+1e-8f);
  int u=p.uv[2*i],v=p.uv[2*i+1];
  float rn=p.rn2[i]; float mn=INFINITY;
  #pragma unroll
  for(int c=0;c<CMAX;c++){
    float a=INFINITY;
    if(c<C){
      int pc=p.Q+c;
      a=rn+p.G[(size_t)pc*p.BN+pc]-(p.G[(size_t)u*p.BN+pc]+p.G[(size_t)v*p.BN+pc]);
      a=fmaxf(a,0.f);
      mn=fminf(mn,a);
    }
    p.amat[(size_t)i*CMAX+c]=a;
  }
  p.dmin[i]=sqrtf(fmaxf(mn,1e-30f));
}

// ---------- median of d (bit-exact) ----------
__global__ void k_medd(P p){
  __shared__ unsigned sLo,sHi; __shared__ int scnt[TPB];
  int n=p.meta[1];
  int target=(n-1)/2;
  if(threadIdx.x==0){sLo=0u;sHi=0xFFFFFFFFu;}
  __syncthreads();
  while(true){
    unsigned lo=sLo,hi=sHi;
    if(lo>=hi)break;
    unsigned mid=lo+((hi-lo)>>1);
    int cnt=0;
    for(int i=threadIdx.x;i<n;i+=blockDim.x) cnt += (f2key(p.dmin[i])<=mid);
    scnt[threadIdx.x]=cnt; __syncthreads();
    for(int s=blockDim.x/2;s>0;s>>=1){
      if(threadIdx.x<s) scnt[threadIdx.x]+=scnt[threadIdx.x+s];
      __syncthreads();
    }
    if(threadIdx.x==0){ if(scnt[0]>=target+1) sHi=mid; else sLo=mid+1; }
    __syncthreads();
  }
  if(threadIdx.x==0){
    float med=key2f(sLo);
    p.meddenom[0]=2.f*med*med+1e-8f;
  }
}

// ---------- lambda, scale, y0 (full 8-wide, INF-padded amat) ----------
__global__ void k_y0(P p){
  int i=blockIdx.x*blockDim.x+threadIdx.x;
  int n=p.meta[1]; if(i>=n)return;
  float la=expf(-(p.dmin[i]*p.dmin[i])/p.meddenom[0]);
  p.scalev[i]=la*p.dinv[i];
  float mn=INFINITY;
  #pragma unroll
  for(int c=0;c<CMAX;c++) mn=fminf(mn,p.amat[(size_t)i*CMAX+c]);
  float ex[CMAX]; float sum=0.f;
  #pragma unroll
  for(int c=0;c<CMAX;c++){
    float e=expf(mn-p.amat[(size_t)i*CMAX+c]);   // INF -> 0
    ex[c]=e; sum+=e;
  }
  float inv=1.f/sum;
  #pragma unroll
  for(int c=0;c<CMAX;c++) p.yA[(size_t)i*CMAX+c]=ex[c]*inv;
}

// ---------- fused label propagation, 8-wide unrolled, light reduces ----------
__global__ void __launch_bounds__(1024) k_iter(P p){
  __shared__ float sred[16];
  __shared__ int sdone;
  int n=p.meta[1]; int k=p.meta[2]; int C=p.meta[0];
  float* cur=p.yA; float* nxt=p.yB;
  int tid=threadIdx.x; int lane=tid&63; int wid=tid>>6;
  int nw=(blockDim.x+63)>>6;
  for(int t=0;t<50;t++){
    float dmx=0.f;
    for(int i=tid;i<n;i+=blockDim.x){
      float4 wa=make_float4(0.f,0.f,0.f,0.f), wb=make_float4(0.f,0.f,0.f,0.f);
      for(int q=0;q<k;q++){
        int j=p.nbrs[(size_t)i*KMAX+q];
        float w=p.wgt[(size_t)i*KMAX+q];
        const float4* yr=(const float4*)(cur+(size_t)j*CMAX);
        float4 y0=yr[0],y1=yr[1];
        wa.x+=w*y0.x; wa.y+=w*y0.y; wa.z+=w*y0.z; wa.w+=w*y0.w;
        wb.x+=w*y1.x; wb.y+=w*y1.y; wb.z+=w*y1.z; wb.w+=w*y1.w;
      }
      int e1=p.inoff[i+1];
      for(int e=p.inoff[i];e<e1;e++){
        int j=p.insrc[e]; float w=p.inw[e];
        const float4* yr=(const float4*)(cur+(size_t)j*CMAX);
        float4 y0=yr[0],y1=yr[1];
        wa.x+=w*y0.x; wa.y+=w*y0.y; wa.z+=w*y0.z; wa.w+=w*y0.w;
        wb.x+=w*y1.x; wb.y+=w*y1.y; wb.z+=w*y1.z; wb.w+=w*y1.w;
      }
      float sc=p.scalev[i]*0.5f;
      const float4* am=(const float4*)(p.amat+(size_t)i*CMAX);
      float4 a0=am[0],a1=am[1];
      float l0=sc*wa.x-a0.x, l1=sc*wa.y-a0.y, l2=sc*wa.z-a0.z, l3=sc*wa.w-a0.w;
      float l4=sc*wb.x-a1.x, l5=sc*wb.y-a1.y, l6=sc*wb.z-a1.z, l7=sc*wb.w-a1.w;
      float mx=fmaxf(fmaxf(fmaxf(l0,l1),fmaxf(l2,l3)),fmaxf(fmaxf(l4,l5),fmaxf(l6,l7)));
      float e0=expf(l0-mx),e1f=expf(l1-mx),e2=expf(l2-mx),e3=expf(l3-mx);
      float e4=expf(l4-mx),e5=expf(l5-mx),e6=expf(l6-mx),e7=expf(l7-mx);
      float inv=1.f/(e0+e1f+e2+e3+e4+e5+e6+e7);
      float4 o0=make_float4(e0*inv,e1f*inv,e2*inv,e3*inv);
      float4 o1=make_float4(e4*inv,e5*inv,e6*inv,e7*inv);
      const float4* cr=(const float4*)(cur+(size_t)i*CMAX);
      float4 c0=cr[0],c1=cr[1];
      dmx=fmaxf(dmx,fabsf(o0.x-c0.x)); dmx=fmaxf(dmx,fabsf(o0.y-c0.y));
      dmx=fmaxf(dmx,fabsf(o0.z-c0.z)); dmx=fmaxf(dmx,fabsf(o0.w-c0.w));
      dmx=fmaxf(dmx,fabsf(o1.x-c1.x)); dmx=fmaxf(dmx,fabsf(o1.y-c1.y));
      dmx=fmaxf(dmx,fabsf(o1.z-c1.z)); dmx=fmaxf(dmx,fabsf(o1.w-c1.w));
      float4* nr=(float4*)(nxt+(size_t)i*CMAX);
      nr[0]=o0; nr[1]=o1;
    }
    #pragma unroll
    for(int s=32;s>=1;s>>=1) dmx=fmaxf(dmx,__shfl_xor(dmx,s,64));
    if(lane==0) sred[wid]=dmx;
    __syncthreads();
    if(tid==0){
      float mm=0.f;
      for(int w2=0;w2<nw;w2++) mm=fmaxf(mm,sred[w2]);
      sdone=(mm<1e-4f)?1:0;
    }
    __syncthreads();
    if(sdone) break;
    float* tmp=cur;cur=nxt;nxt=tmp;
  }
  __syncthreads();
  for(int q=tid;q<p.Q;q+=blockDim.x){
    float best=cur[(size_t)q*CMAX+0]; int bc=0;
    for(int c=1;c<C;c++){
      float v=cur[(size_t)q*CMAX+c];
      if(v>best){best=v;bc=c;}
    }
    p.outp[q]=bc;
  }
}

// =======================================================================

static void make_layout(char* base,int S,int Q,int D,int BN,long N,
                        const float*fs,const int*ys,const float*fq,
                        int* outp, P* pp, size_t* need){
  size_t off=0;
  auto A=[&](size_t b)->char*{
    size_t o=(off+255)&~(size_t)255; off=o+b; return base+o;
  };
  P p{};
  p.fs=fs;p.ys=ys;p.fq=fq;p.S=S;p.Q=Q;p.D=D;p.BN=BN;p.NMAX=(int)N;
  p.proto=(float*)A(4ul*CMAX*D);
  p.G=(float*)A(4ul*(size_t)BN*BN);
  p.cosq=(float*)A(4ul*(size_t)Q*Q);
  p.ybt=(int*)A(4ul*Q);
  p.cls=(int*)A(4ul*CMAX);
  p.scount=(int*)A(4ul*CMAX);
  p.qcount=(int*)A(4ul*CMAX);
  p.qidx=(int*)A(4ul*CMAX*Q);
  p.kq=(int*)A(4ul*CMAX);
  p.thr=(float*)A(4ul*CMAX);
  p.rowcnt=(int*)A(4ul*CMAX*Q);
  p.rowoff=(int*)A(4ul*CMAX*Q);
  p.paircnt=(int*)A(4ul*CMAX);
  p.basev=(int*)A(4ul*CMAX);
  p.meta=(int*)A(4ul*16);
  p.uv=(int*)A(8ul*N);
  p.rn2=(float*)A(4ul*N);
  p.nbrs=(int*)A(4ul*KMAX*N);
  p.dnb=(float*)A(4ul*KMAX*N);
  p.wgt=(float*)A(4ul*KMAX*N);
  p.sigma=(float*)A(4ul*N);
  p.indeg=(int*)A(4ul*N);
  p.inoff=(int*)A(4ul*(N+1));
  p.cursor=(int*)A(4ul*N);
  p.insrcU=(int*)A(4ul*KMAX*N);
  p.inwU=(float*)A(4ul*KMAX*N);
  p.indst=(int*)A(4ul*KMAX*N);
  p.insrc=(int*)A(4ul*KMAX*N);
  p.inw=(float*)A(4ul*KMAX*N);
  p.amat=(float*)A(4ul*CMAX*N);
  p.dinv=(float*)A(4ul*N);
  p.dmin=(float*)A(4ul*N);
  p.scalev=(float*)A(4ul*N);
  p.yA=(float*)A(4ul*CMAX*N);
  p.yB=(float*)A(4ul*CMAX*N);
  p.meddenom=(float*)A(4ul*4);
  p.outp=outp;
  *pp=p; *need=off;
}

extern "C" void kernel_launch(void* const* d_in, const int* in_sizes, int n_in,
                              void* d_out, int out_size, void* d_ws, size_t ws_size,
                              hipStream_t stream){
  const float* fs=(const float*)d_in[0];
  const int*   ys=(const int*)d_in[1];
  const float* fq=(const float*)d_in[2];
  int S=in_sizes[1];
  int D=in_sizes[0]/S;
  int Q=in_sizes[2]/D;
  int BN=Q+CMAX;

  long full=(long)Q + (long)Q*(Q-1)/2 + CMAX;   // absolute worst-case n
  long cand[4]={full,16384,8192,5000};
  P p{}; size_t need=0; int NMAX=(int)cand[3];
  for(int ci=0;ci<4;ci++){
    long N=cand[ci]; if(N<Q+CMAX)N=Q+CMAX;
    make_layout((char*)d_ws,S,Q,D,BN,N,fs,ys,fq,(int*)d_out,&p,&need);
    NMAX=(int)N;
    if(need<=ws_size) break;
  }

  int gN=(NMAX+TPB-1)/TPB;
  long gEl=((long)NMAX*KMAX+TPB-1)/TPB;
  int gE=(int)gEl;

  k_init   <<<1, 64, 0, stream>>>(p);
  k_proto  <<<CMAX, TPB, 0, stream>>>(p);
  k_gram   <<<BN, TPB, 0, stream>>>(p);
  k_cos    <<<(Q*Q+TPB-1)/TPB, TPB, 0, stream>>>(p);
  k_yboot  <<<(Q+TPB-1)/TPB, TPB, 0, stream>>>(p);
  k_qidx   <<<CMAX, 64, 0, stream>>>(p);
  k_median <<<CMAX, TPB, 0, stream>>>(p);
  k_rowcnt <<<CMAX, TPB, 0, stream>>>(p);
  k_bases  <<<1, 1, 0, stream>>>(p);
  k_uv     <<<gN, TPB, 0, stream>>>(p);
  k_uvpairs<<<CMAX, TPB, 0, stream>>>(p);
  k_rn2    <<<gN, TPB, 0, stream>>>(p);
  k_knn    <<<NMAX, 64, 0, stream>>>(p);
  k_wgt    <<<gN, TPB, 0, stream>>>(p);
  k_count  <<<gN, TPB, 0, stream>>>(p);
  k_scan   <<<1, TPB, 0, stream>>>(p);
  k_fill   <<<gN, TPB, 0, stream>>>(p);
  k_rank   <<<gE, TPB, 0, stream>>>(p);
  k_dad    <<<gN, TPB, 0, stream>>>(p);
  k_medd   <<<1, TPB, 0, stream>>>(p);
  k_y0     <<<gN, TPB, 0, stream>>>(p);
  k_iter   <<<1, 1024, 0, stream>>>(p);
}

// Round 4
// 992.419 us; speedup vs baseline: 3.2766x; 1.7704x over previous
//
#include <hip/hip_runtime.h>
#include <math.h>

#define CMAX 8
#define KMAX 16
#define TPB 256
#define BNMAX 512

struct P {
  const float* fs; const int* ys; const float* fq;
  int S, Q, D, BN, NMAX;
  float* proto;
  float* G;
  float* cosq;
  int* ybt;
  int* cls; int* scount; int* qcount; int* qidx; int* kq;
  float* thr;
  int* rowcnt; int* rowoff; int* paircnt; int* basev;
  int* meta;     // [0]=C [1]=n [2]=k
  int* uv;
  float* rn2;
  int* nbrs; float* dnb; float* wgt; float* sigma;
  int* indeg; int* inoff; int* cursor;
  int* insrcU; float* inwU; int* indst;   // unsorted transpose edges
  int* insrc; float* inw;                 // rank-sorted transpose edges
  unsigned* cosk;                         // per-class gathered cos keys
  float* amat; float* dinv; float* dmin; float* scalev;
  float* yA; float* yB;
  float* meddenom;
  int* outp;
};

__device__ inline unsigned f2key(float f){
  unsigned b=__float_as_uint(f);
  return (b&0x80000000u)? ~b : (b|0x80000000u);
}
__device__ inline float key2f(unsigned k){
  unsigned b=(k&0x80000000u)? (k^0x80000000u) : ~k;
  return __uint_as_float(b);
}
__device__ inline unsigned long long shfl_xor_u64(unsigned long long v,int m){
  unsigned lo=(unsigned)v, hi=(unsigned)(v>>32);
  lo=__shfl_xor(lo,m,64); hi=__shfl_xor(hi,m,64);
  return (((unsigned long long)hi)<<32)|lo;
}

// ---------- setup: unique classes + support counts ----------
__global__ void k_init(P p){
  if (threadIdx.x==0){
    int labs[CMAX]; int cnt[CMAX]; int C=0;
    for (int s=0;s<p.S;s++){
      int l=p.ys[s]; int f=-1;
      for(int c=0;c<C;c++) if(labs[c]==l){f=c;break;}
      if(f<0){ if(C<CMAX){labs[C]=l;cnt[C]=1;C++;} }
      else cnt[f]++;
    }
    for(int a=0;a<C;a++)for(int b=a+1;b<C;b++)
      if(labs[b]<labs[a]){int t=labs[a];labs[a]=labs[b];labs[b]=t;
                          t=cnt[a];cnt[a]=cnt[b];cnt[b]=t;}
    for(int c=0;c<C;c++){p.cls[c]=labs[c];p.scount[c]=cnt[c];}
    p.meta[0]=C;
  }
}

// ---------- prototypes ----------
__global__ void k_proto(P p){
  int c=blockIdx.x; int C=p.meta[0];
  for(int d=threadIdx.x; d<p.D; d+=blockDim.x){
    float s=0.f;
    if(c<C){
      int lab=p.cls[c];
      for(int j=0;j<p.S;j++) if(p.ys[j]==lab) s+=p.fs[(size_t)j*p.D+d];
      s/= (float)p.scount[c];
    }
    p.proto[(size_t)c*p.D+d]=s;
  }
}

// ---------- Gram matrix over B = [feat_q ; prototypes], float4 inner ----------
__global__ void k_gram(P p){
  __shared__ float arow[1024];
  int a=blockIdx.x;
  const float* ra = (a<p.Q)? p.fq + (size_t)a*p.D : p.proto + (size_t)(a-p.Q)*p.D;
  const float* A = ra;
  if(p.D<=1024){
    for(int d=threadIdx.x; d<p.D; d+=blockDim.x) arow[d]=ra[d];
    __syncthreads();
    A=(const float*)arow;
  }
  int D4=p.D>>2; int Dt=D4<<2;
  for(int b=threadIdx.x; b<p.BN; b+=blockDim.x){
    const float* rb=(b<p.Q)? p.fq+(size_t)b*p.D : p.proto+(size_t)(b-p.Q)*p.D;
    const float4* a4=(const float4*)A;
    const float4* b4=(const float4*)rb;
    float s=0.f;
    #pragma unroll 4
    for(int d=0;d<D4;d++){
      float4 x=a4[d], y=b4[d];
      s += x.x*y.x + x.y*y.y + x.z*y.z + x.w*y.w;
    }
    for(int d=Dt;d<p.D;d++) s += A[d]*rb[d];
    p.G[(size_t)a*p.BN+b]=s;
  }
}

// ---------- cosine matrix of queries ----------
__global__ void k_cos(P p){
  int t=blockIdx.x*blockDim.x+threadIdx.x;
  if(t>=p.Q*p.Q)return;
  int i=t/p.Q, j=t%p.Q;
  p.cosq[t]=p.G[(size_t)i*p.BN+j]/(sqrtf(p.G[(size_t)i*p.BN+i])*sqrtf(p.G[(size_t)j*p.BN+j]));
}

// ---------- bootstrap labels ----------
__global__ void k_yboot(P p){
  int q=blockIdx.x*blockDim.x+threadIdx.x;
  if(q>=p.Q)return;
  int C=p.meta[0];
  float gq=p.G[(size_t)q*p.BN+q];
  float best=INFINITY; int bc=0;
  for(int c=0;c<C;c++){
    int pc=p.Q+c;
    float d2=gq+p.G[(size_t)pc*p.BN+pc]-2.f*p.G[(size_t)q*p.BN+pc];
    d2=fmaxf(d2,0.f);
    if(d2<best){best=d2;bc=c;}
  }
  p.ybt[q]=bc;
}

// ---------- per-class index lists + kq: wave-parallel ballot compaction ----------
__global__ void k_qidx(P p){
  int c=blockIdx.x; int C=p.meta[0];
  int lane=threadIdx.x;
  if(c>=C){ if(lane==0){p.qcount[c]=0;p.kq[c]=0;} return; }
  int base=0;
  for(int q0=0;q0<p.Q;q0+=64){
    int q=q0+lane;
    bool in = (q<p.Q) && (p.ybt[q]==c);
    unsigned long long mask=__ballot(in);
    int pre=__popcll(mask & ((lane==63)?0x7FFFFFFFFFFFFFFFull:((1ull<<lane)-1ull)));
    if(in) p.qidx[c*p.Q+base+pre]=q;
    base+=__popcll(mask);
  }
  if(lane==0) p.qcount[c]=base;
  // kq: argmin over the class's queries of dist to proto c (first-min wins)
  int pc=p.Q+c;
  float gp=p.G[(size_t)pc*p.BN+pc];
  unsigned long long best=0xFFFFFFFFFFFFFFFFull;
  for(int t=lane;t<base;t+=64){
    int q=p.qidx[c*p.Q+t];
    float d2=fmaxf(p.G[(size_t)q*p.BN+q]+gp-2.f*p.G[(size_t)q*p.BN+pc],0.f);
    unsigned long long key=(((unsigned long long)f2key(d2))<<32)|(unsigned)t;
    if(key<best)best=key;
  }
  #pragma unroll
  for(int s=32;s>=1;s>>=1){
    unsigned long long o=shfl_xor_u64(best,s);
    if(o<best)best=o;
  }
  if(lane==0){
    int t=(int)(unsigned)(best&0xFFFFFFFFull);
    p.kq[c]=(base>0)? p.qidx[c*p.Q+t] : 0;
  }
}

// ---------- per-class median: gather keys once + 4-pass radix select ----------
__global__ void k_median(P p){
  __shared__ unsigned hist[256];
  __shared__ unsigned sPref; __shared__ int sTrem;
  __shared__ int sqidx[512];
  int c=blockIdx.x; int C=p.meta[0];
  int m=(c<C)? p.qcount[c]:0;
  int tid=threadIdx.x;
  if(m<2){ if(tid==0) p.thr[c]=INFINITY; return; }
  const int* qix;
  if(p.Q<=512){
    for(int t=tid;t<m;t+=blockDim.x) sqidx[t]=p.qidx[c*p.Q+t];
    __syncthreads();
    qix=sqidx;
  } else qix=p.qidx+c*p.Q;
  int total=m*m;
  unsigned* keys=p.cosk+(size_t)c*p.Q*p.Q;
  for(int t=tid;t<total;t+=blockDim.x){
    int a=t/m, b=t-a*m;
    keys[t]=f2key(p.cosq[(size_t)qix[a]*p.Q+qix[b]]);
  }
  if(tid==0){ sPref=0u; sTrem=(total-1)/2; }
  __syncthreads();
  unsigned prefmask=0u;
  for(int shift=24;shift>=0;shift-=8){
    hist[tid&255]=0u;      // blockDim>=256
    __syncthreads();
    unsigned pref=sPref;
    for(int t=tid;t<total;t+=blockDim.x){
      unsigned key=keys[t];
      if((key&prefmask)==pref) atomicAdd(&hist[(key>>shift)&255],1u);
    }
    __syncthreads();
    if(tid==0){
      int trem=sTrem; unsigned cum=0;
      for(int b=0;b<256;b++){
        unsigned h=hist[b];
        if(cum+h>(unsigned)trem){ sPref=pref|((unsigned)b<<shift); sTrem=trem-(int)cum; break; }
        cum+=h;
      }
    }
    __syncthreads();
    prefmask|=(0xFFu<<shift);
  }
  if(tid==0) p.thr[c]=key2f(sPref);
}

// ---------- per-class pair row-counts + prefix ----------
__global__ void k_rowcnt(P p){
  int c=blockIdx.x; int C=p.meta[0];
  int m=(c<C)? p.qcount[c]:0;
  if(m<2){ if(threadIdx.x==0) p.paircnt[c]=0; return; }
  float th=p.thr[c];
  for(int a=threadIdx.x;a<m;a+=blockDim.x){
    int ia=p.qidx[c*p.Q+a]; int cnt=0;
    const float* row=p.cosq+(size_t)ia*p.Q;
    for(int b=a+1;b<m;b++){
      int ib=p.qidx[c*p.Q+b];
      cnt += (row[ib]>=th);
    }
    p.rowcnt[c*p.Q+a]=cnt;
  }
  __syncthreads();
  if(threadIdx.x==0){
    int run=0;
    for(int a=0;a<m;a++){p.rowoff[c*p.Q+a]=run; run+=p.rowcnt[c*p.Q+a];}
    p.paircnt[c]=run;
  }
}

// ---------- bases, n, k ----------
__global__ void k_bases(P p){
  int C=p.meta[0]; int cur=p.Q;
  for(int c=0;c<C;c++){
    p.basev[c]=cur;
    if(p.qcount[c]>=2) cur += p.paircnt[c]+1;
  }
  int n=cur; if(n>p.NMAX)n=p.NMAX;
  p.meta[1]=n;
  int k=31-__clz(n); if(k<1)k=1; if(k>KMAX-1)k=KMAX-1;
  p.meta[2]=k;
}

// ---------- uv for query rows + zero indeg ----------
__global__ void k_uv(P p){
  int r=blockIdx.x*blockDim.x+threadIdx.x;
  if(r>=p.NMAX)return;
  p.indeg[r]=0;
  if(r<p.Q){ p.uv[2*r]=r; p.uv[2*r+1]=r; }
}

// ---------- uv for virtual rows ----------
__global__ void k_uvpairs(P p){
  int c=blockIdx.x; int C=p.meta[0];
  int m=(c<C)? p.qcount[c]:0;
  if(m<2)return;
  float th=p.thr[c];
  int bs=p.basev[c];
  for(int a=threadIdx.x;a<m;a+=blockDim.x){
    int ia=p.qidx[c*p.Q+a];
    int off=bs+p.rowoff[c*p.Q+a]; int cnt=0;
    const float* row=p.cosq+(size_t)ia*p.Q;
    for(int b=a+1;b<m;b++){
      int ib=p.qidx[c*p.Q+b];
      if(row[ib]>=th){
        int r=off+cnt;
        p.uv[2*r]=ia; p.uv[2*r+1]=ib;
        cnt++;
      }
    }
  }
  if(threadIdx.x==0){
    int r=bs+p.paircnt[c];
    p.uv[2*r]=p.Q+c; p.uv[2*r+1]=p.kq[c];
  }
}

// ---------- per-row norm^2 from Gram ----------
__global__ void k_rn2(P p){
  int r=blockIdx.x*blockDim.x+threadIdx.x;
  int n=p.meta[1]; if(r>=n)return;
  int u=p.uv[2*r],v=p.uv[2*r+1];
  p.rn2[r]=0.25f*(p.G[(size_t)u*p.BN+u]+2.f*p.G[(size_t)u*p.BN+v]+p.G[(size_t)v*p.BN+v]);
}

// ---------- kNN: 1 wave per row, register top-16 via u64 keys ----------
__global__ void k_knn(P p){
  __shared__ float sGu[BNMAX];
  __shared__ float sGv[BNMAX];
  int i=blockIdx.x;
  int n=p.meta[1]; if(i>=n)return;
  int kp1=p.meta[2]+1;
  int lane=threadIdx.x;
  int u1=p.uv[2*i], v1=p.uv[2*i+1];
  const float* Gu=p.G+(size_t)u1*p.BN;
  const float* Gv=p.G+(size_t)v1*p.BN;
  const float* bu=Gu; const float* bv=Gv;
  if(p.BN<=BNMAX){
    for(int d=lane; d<p.BN; d+=64){ sGu[d]=Gu[d]; sGv[d]=Gv[d]; }
    __syncthreads();
    bu=(const float*)sGu; bv=(const float*)sGv;
  }
  float rni=p.rn2[i];
  unsigned long long r[16];
  #pragma unroll
  for(int t=0;t<16;t++) r[t]=0xFFFFFFFFFFFFFFFFull;
  for(int j=lane;j<n;j+=64){
    int2 w=((const int2*)p.uv)[j];
    float dot=0.25f*(bu[w.x]+bu[w.y]+bv[w.x]+bv[w.y]);
    float d2=fmaxf(rni+p.rn2[j]-2.f*dot,0.f);
    unsigned long long key=(((unsigned long long)f2key(d2))<<32)|(unsigned)j;
    if(key<r[15]){
      #pragma unroll
      for(int t=0;t<16;t++){
        unsigned long long lo=key<r[t]?key:r[t];
        unsigned long long hi=key<r[t]?r[t]:key;
        r[t]=lo; key=hi;
      }
    }
  }
  for(int t=0;t<kp1;t++){
    unsigned long long m=r[0];
    #pragma unroll
    for(int s=32;s>=1;s>>=1){
      unsigned long long o=shfl_xor_u64(m,s);
      if(o<m)m=o;
    }
    if(r[0]==m){            // unique keys -> exactly one lane pops
      #pragma unroll
      for(int q=0;q<15;q++) r[q]=r[q+1];
      r[15]=0xFFFFFFFFFFFFFFFFull;
    }
    if(lane==0){
      int j=(int)(unsigned)(m&0xFFFFFFFFull);
      float d2=key2f((unsigned)(m>>32));
      float dd=sqrtf(fmaxf(d2,1e-30f));
      if(t>=1){ p.nbrs[(size_t)i*KMAX+t-1]=j; p.dnb[(size_t)i*KMAX+t-1]=dd; }
      if(t==kp1-1) p.sigma[i]=dd+1e-8f;
    }
  }
}

// ---------- edge weights ----------
__global__ void k_wgt(P p){
  int i=blockIdx.x*blockDim.x+threadIdx.x;
  int n=p.meta[1]; if(i>=n)return;
  int k=p.meta[2];
  float si=p.sigma[i];
  for(int q=0;q<k;q++){
    int j=p.nbrs[(size_t)i*KMAX+q];
    p.wgt[(size_t)i*KMAX+q]=expf(-p.dnb[(size_t)i*KMAX+q]/(si*p.sigma[j]));
  }
}

// ---------- in-degree count ----------
__global__ void k_count(P p){
  int i=blockIdx.x*blockDim.x+threadIdx.x;
  int n=p.meta[1]; if(i>=n)return;
  int k=p.meta[2];
  for(int q=0;q<k;q++) atomicAdd(&p.indeg[p.nbrs[(size_t)i*KMAX+q]],1);
}

// ---------- exclusive scan of indeg ----------
__global__ void k_scan(P p){
  __shared__ int part[TPB];
  int n=p.meta[1];
  int chunk=(n+TPB-1)/TPB;
  int beg=threadIdx.x*chunk, end=beg+chunk; if(end>n)end=n;
  int s=0;
  for(int i=beg;i<end;i++) s+=p.indeg[i];
  part[threadIdx.x]=s; __syncthreads();
  if(threadIdx.x==0){
    int run=0;
    for(int t=0;t<TPB;t++){int v=part[t];part[t]=run;run+=v;}
    p.inoff[n]=run;
  }
  __syncthreads();
  int run=part[threadIdx.x];
  for(int i=beg;i<end;i++){
    p.inoff[i]=run; p.cursor[i]=run; run+=p.indeg[i];
  }
}

// ---------- fill transpose edges (unsorted, atomic slots) ----------
__global__ void k_fill(P p){
  int i=blockIdx.x*blockDim.x+threadIdx.x;
  int n=p.meta[1]; if(i>=n)return;
  int k=p.meta[2];
  for(int q=0;q<k;q++){
    int dst=p.nbrs[(size_t)i*KMAX+q];
    int slot=atomicAdd(&p.cursor[dst],1);
    p.insrcU[slot]=i; p.inwU[slot]=p.wgt[(size_t)i*KMAX+q]; p.indst[slot]=dst;
  }
}

// ---------- deterministic order: thread-per-edge rank-by-count ----------
__global__ void k_rank(P p){
  int e=blockIdx.x*blockDim.x+threadIdx.x;
  int n=p.meta[1];
  int E=p.inoff[n];
  if(e>=E)return;
  int dst=p.indst[e];
  int b=p.inoff[dst], en=p.inoff[dst+1];
  int s=p.insrcU[e]; float w=p.inwU[e];
  int rank=0;
  for(int x=b;x<en;x++) rank += (p.insrcU[x]<s);
  p.insrc[b+rank]=s; p.inw[b+rank]=w;
}

// ---------- D_inv, a-matrix (+INF padding), d_min ----------
__global__ void k_dad(P p){
  int i=blockIdx.x*blockDim.x+threadIdx.x;
  int n=p.meta[1]; if(i>=n)return;
  int k=p.meta[2]; int C=p.meta[0];
  float s=0.f;
  for(int q=0;q<k;q++) s+=p.wgt[(size_t)i*KMAX+q];
  for(int e=p.inoff[i];e<p.inoff[i+1];e++) s+=p.inw[e];
  p.dinv[i]=1.f/(0.5f*s+1e-8f);
  int u=p.uv[2*i],v=p.uv[2*i+1];
  float rn=p.rn2[i]; float mn=INFINITY;
  #pragma unroll
  for(int c=0;c<CMAX;c++){
    float a=INFINITY;
    if(c<C){
      int pc=p.Q+c;
      a=rn+p.G[(size_t)pc*p.BN+pc]-(p.G[(size_t)u*p.BN+pc]+p.G[(size_t)v*p.BN+pc]);
      a=fmaxf(a,0.f);
      mn=fminf(mn,a);
    }
    p.amat[(size_t)i*CMAX+c]=a;
  }
  p.dmin[i]=sqrtf(fmaxf(mn,1e-30f));
}

// ---------- median of d: 4-pass radix select ----------
__global__ void k_medd(P p){
  __shared__ unsigned hist[256];
  __shared__ unsigned sPref; __shared__ int sTrem;
  int n=p.meta[1];
  int tid=threadIdx.x;
  if(tid==0){ sPref=0u; sTrem=(n-1)/2; }
  __syncthreads();
  unsigned prefmask=0u;
  for(int shift=24;shift>=0;shift-=8){
    hist[tid&255]=0u;
    __syncthreads();
    unsigned pref=sPref;
    for(int i=tid;i<n;i+=blockDim.x){
      unsigned key=f2key(p.dmin[i]);
      if((key&prefmask)==pref) atomicAdd(&hist[(key>>shift)&255],1u);
    }
    __syncthreads();
    if(tid==0){
      int trem=sTrem; unsigned cum=0;
      for(int b=0;b<256;b++){
        unsigned h=hist[b];
        if(cum+h>(unsigned)trem){ sPref=pref|((unsigned)b<<shift); sTrem=trem-(int)cum; break; }
        cum+=h;
      }
    }
    __syncthreads();
    prefmask|=(0xFFu<<shift);
  }
  if(tid==0){
    float med=key2f(sPref);
    p.meddenom[0]=2.f*med*med+1e-8f;
  }
}

// ---------- lambda, scale, y0 (full 8-wide, INF-padded amat) ----------
__global__ void k_y0(P p){
  int i=blockIdx.x*blockDim.x+threadIdx.x;
  int n=p.meta[1]; if(i>=n)return;
  float la=expf(-(p.dmin[i]*p.dmin[i])/p.meddenom[0]);
  p.scalev[i]=la*p.dinv[i];
  float mn=INFINITY;
  #pragma unroll
  for(int c=0;c<CMAX;c++) mn=fminf(mn,p.amat[(size_t)i*CMAX+c]);
  float ex[CMAX]; float sum=0.f;
  #pragma unroll
  for(int c=0;c<CMAX;c++){
    float e=expf(mn-p.amat[(size_t)i*CMAX+c]);   // INF -> 0
    ex[c]=e; sum+=e;
  }
  float inv=1.f/sum;
  #pragma unroll
  for(int c=0;c<CMAX;c++) p.yA[(size_t)i*CMAX+c]=ex[c]*inv;
}

// ---------- fused label propagation, 8-wide unrolled, light reduces ----------
__global__ void __launch_bounds__(1024) k_iter(P p){
  __shared__ float sred[16];
  __shared__ int sdone;
  int n=p.meta[1]; int k=p.meta[2]; int C=p.meta[0];
  float* cur=p.yA; float* nxt=p.yB;
  int tid=threadIdx.x; int lane=tid&63; int wid=tid>>6;
  int nw=(blockDim.x+63)>>6;
  for(int t=0;t<50;t++){
    float dmx=0.f;
    for(int i=tid;i<n;i+=blockDim.x){
      float4 wa=make_float4(0.f,0.f,0.f,0.f), wb=make_float4(0.f,0.f,0.f,0.f);
      for(int q=0;q<k;q++){
        int j=p.nbrs[(size_t)i*KMAX+q];
        float w=p.wgt[(size_t)i*KMAX+q];
        const float4* yr=(const float4*)(cur+(size_t)j*CMAX);
        float4 y0=yr[0],y1=yr[1];
        wa.x+=w*y0.x; wa.y+=w*y0.y; wa.z+=w*y0.z; wa.w+=w*y0.w;
        wb.x+=w*y1.x; wb.y+=w*y1.y; wb.z+=w*y1.z; wb.w+=w*y1.w;
      }
      int e1=p.inoff[i+1];
      for(int e=p.inoff[i];e<e1;e++){
        int j=p.insrc[e]; float w=p.inw[e];
        const float4* yr=(const float4*)(cur+(size_t)j*CMAX);
        float4 y0=yr[0],y1=yr[1];
        wa.x+=w*y0.x; wa.y+=w*y0.y; wa.z+=w*y0.z; wa.w+=w*y0.w;
        wb.x+=w*y1.x; wb.y+=w*y1.y; wb.z+=w*y1.z; wb.w+=w*y1.w;
      }
      float sc=p.scalev[i]*0.5f;
      const float4* am=(const float4*)(p.amat+(size_t)i*CMAX);
      float4 a0=am[0],a1=am[1];
      float l0=sc*wa.x-a0.x, l1=sc*wa.y-a0.y, l2=sc*wa.z-a0.z, l3=sc*wa.w-a0.w;
      float l4=sc*wb.x-a1.x, l5=sc*wb.y-a1.y, l6=sc*wb.z-a1.z, l7=sc*wb.w-a1.w;
      float mx=fmaxf(fmaxf(fmaxf(l0,l1),fmaxf(l2,l3)),fmaxf(fmaxf(l4,l5),fmaxf(l6,l7)));
      float e0=expf(l0-mx),e1f=expf(l1-mx),e2=expf(l2-mx),e3=expf(l3-mx);
      float e4=expf(l4-mx),e5=expf(l5-mx),e6=expf(l6-mx),e7=expf(l7-mx);
      float inv=1.f/(e0+e1f+e2+e3+e4+e5+e6+e7);
      float4 o0=make_float4(e0*inv,e1f*inv,e2*inv,e3*inv);
      float4 o1=make_float4(e4*inv,e5*inv,e6*inv,e7*inv);
      const float4* cr=(const float4*)(cur+(size_t)i*CMAX);
      float4 c0=cr[0],c1=cr[1];
      dmx=fmaxf(dmx,fabsf(o0.x-c0.x)); dmx=fmaxf(dmx,fabsf(o0.y-c0.y));
      dmx=fmaxf(dmx,fabsf(o0.z-c0.z)); dmx=fmaxf(dmx,fabsf(o0.w-c0.w));
      dmx=fmaxf(dmx,fabsf(o1.x-c1.x)); dmx=fmaxf(dmx,fabsf(o1.y-c1.y));
      dmx=fmaxf(dmx,fabsf(o1.z-c1.z)); dmx=fmaxf(dmx,fabsf(o1.w-c1.w));
      float4* nr=(float4*)(nxt+(size_t)i*CMAX);
      nr[0]=o0; nr[1]=o1;
    }
    #pragma unroll
    for(int s=32;s>=1;s>>=1) dmx=fmaxf(dmx,__shfl_xor(dmx,s,64));
    if(lane==0) sred[wid]=dmx;
    __syncthreads();
    if(tid==0){
      float mm=0.f;
      for(int w2=0;w2<nw;w2++) mm=fmaxf(mm,sred[w2]);
      sdone=(mm<1e-4f)?1:0;
    }
    __syncthreads();
    if(sdone) break;
    float* tmp=cur;cur=nxt;nxt=tmp;
  }
  __syncthreads();
  for(int q=tid;q<p.Q;q+=blockDim.x){
    float best=cur[(size_t)q*CMAX+0]; int bc=0;
    for(int c=1;c<C;c++){
      float v=cur[(size_t)q*CMAX+c];
      if(v>best){best=v;bc=c;}
    }
    p.outp[q]=bc;
  }
}

// =======================================================================

static void make_layout(char* base,int S,int Q,int D,int BN,long N,
                        const float*fs,const int*ys,const float*fq,
                        int* outp, P* pp, size_t* need){
  size_t off=0;
  auto A=[&](size_t b)->char*{
    size_t o=(off+255)&~(size_t)255; off=o+b; return base+o;
  };
  P p{};
  p.fs=fs;p.ys=ys;p.fq=fq;p.S=S;p.Q=Q;p.D=D;p.BN=BN;p.NMAX=(int)N;
  p.proto=(float*)A(4ul*CMAX*D);
  p.G=(float*)A(4ul*(size_t)BN*BN);
  p.cosq=(float*)A(4ul*(size_t)Q*Q);
  p.ybt=(int*)A(4ul*Q);
  p.cls=(int*)A(4ul*CMAX);
  p.scount=(int*)A(4ul*CMAX);
  p.qcount=(int*)A(4ul*CMAX);
  p.qidx=(int*)A(4ul*CMAX*Q);
  p.kq=(int*)A(4ul*CMAX);
  p.thr=(float*)A(4ul*CMAX);
  p.rowcnt=(int*)A(4ul*CMAX*Q);
  p.rowoff=(int*)A(4ul*CMAX*Q);
  p.paircnt=(int*)A(4ul*CMAX);
  p.basev=(int*)A(4ul*CMAX);
  p.meta=(int*)A(4ul*16);
  p.uv=(int*)A(8ul*N);
  p.rn2=(float*)A(4ul*N);
  p.nbrs=(int*)A(4ul*KMAX*N);
  p.dnb=(float*)A(4ul*KMAX*N);
  p.wgt=(float*)A(4ul*KMAX*N);
  p.sigma=(float*)A(4ul*N);
  p.indeg=(int*)A(4ul*N);
  p.inoff=(int*)A(4ul*(N+1));
  p.cursor=(int*)A(4ul*N);
  p.insrcU=(int*)A(4ul*KMAX*N);
  p.inwU=(float*)A(4ul*KMAX*N);
  p.indst=(int*)A(4ul*KMAX*N);
  p.insrc=(int*)A(4ul*KMAX*N);
  p.inw=(float*)A(4ul*KMAX*N);
  p.cosk=(unsigned*)A(4ul*CMAX*(size_t)Q*Q);
  p.amat=(float*)A(4ul*CMAX*N);
  p.dinv=(float*)A(4ul*N);
  p.dmin=(float*)A(4ul*N);
  p.scalev=(float*)A(4ul*N);
  p.yA=(float*)A(4ul*CMAX*N);
  p.yB=(float*)A(4ul*CMAX*N);
  p.meddenom=(float*)A(4ul*4);
  p.outp=outp;
  *pp=p; *need=off;
}

extern "C" void kernel_launch(void* const* d_in, const int* in_sizes, int n_in,
                              void* d_out, int out_size, void* d_ws, size_t ws_size,
                              hipStream_t stream){
  const float* fs=(const float*)d_in[0];
  const int*   ys=(const int*)d_in[1];
  const float* fq=(const float*)d_in[2];
  int S=in_sizes[1];
  int D=in_sizes[0]/S;
  int Q=in_sizes[2]/D;
  int BN=Q+CMAX;

  long full=(long)Q + (long)Q*(Q-1)/2 + CMAX;   // absolute worst-case n
  long cand[4]={full,16384,8192,5000};
  P p{}; size_t need=0; int NMAX=(int)cand[3];
  for(int ci=0;ci<4;ci++){
    long N=cand[ci]; if(N<Q+CMAX)N=Q+CMAX;
    make_layout((char*)d_ws,S,Q,D,BN,N,fs,ys,fq,(int*)d_out,&p,&need);
    NMAX=(int)N;
    if(need<=ws_size) break;
  }

  int gN=(NMAX+TPB-1)/TPB;
  long gEl=((long)NMAX*KMAX+TPB-1)/TPB;
  int gE=(int)gEl;

  k_init   <<<1, 64, 0, stream>>>(p);
  k_proto  <<<CMAX, TPB, 0, stream>>>(p);
  k_gram   <<<BN, TPB, 0, stream>>>(p);
  k_cos    <<<(Q*Q+TPB-1)/TPB, TPB, 0, stream>>>(p);
  k_yboot  <<<(Q+TPB-1)/TPB, TPB, 0, stream>>>(p);
  k_qidx   <<<CMAX, 64, 0, stream>>>(p);
  k_median <<<CMAX, TPB, 0, stream>>>(p);
  k_rowcnt <<<CMAX, TPB, 0, stream>>>(p);
  k_bases  <<<1, 1, 0, stream>>>(p);
  k_uv     <<<gN, TPB, 0, stream>>>(p);
  k_uvpairs<<<CMAX, TPB, 0, stream>>>(p);
  k_rn2    <<<gN, TPB, 0, stream>>>(p);
  k_knn    <<<NMAX, 64, 0, stream>>>(p);
  k_wgt    <<<gN, TPB, 0, stream>>>(p);
  k_count  <<<gN, TPB, 0, stream>>>(p);
  k_scan   <<<1, TPB, 0, stream>>>(p);
  k_fill   <<<gN, TPB, 0, stream>>>(p);
  k_rank   <<<gE, TPB, 0, stream>>>(p);
  k_dad    <<<gN, TPB, 0, stream>>>(p);
  k_medd   <<<1, TPB, 0, stream>>>(p);
  k_y0     <<<gN, TPB, 0, stream>>>(p);
  k_iter   <<<1, 1024, 0, stream>>>(p);
}

// Round 5
// 611.485 us; speedup vs baseline: 5.3178x; 1.6230x over previous
//
#include <hip/hip_runtime.h>
#include <math.h>

#define CMAX 8
#define KMAX 16
#define TPB 256
#define BNMAX 512

struct P {
  const float* fs; const int* ys; const float* fq;
  int S, Q, D, BN, NMAX;
  float* proto;
  float* G;
  float* cosq;
  int* ybt;
  int* cls; int* scount; int* qcount; int* qidx; int* kq;
  float* thr;
  int* rowcnt; int* rowoff; int* paircnt; int* basev;
  int* meta;     // [0]=C [1]=n [2]=k [3]=done [4]=parity [5]=blkctr
  int* uv;
  float* rn2;
  int* nbrs; float* dnb; float* wgt; float* sigma;
  int* indeg; int* inoff; int* cursor;
  int* insrcU; float* inwU; int* indst;   // unsorted transpose edges
  int* insrc; float* inw;                 // rank-sorted transpose edges
  unsigned* cosk;                         // per-class gathered cos keys
  unsigned* gmaxu;                        // per-iteration max |dy| (uint bits)
  float* amat; float* dinv; float* dmin; float* scalev;
  float* yA; float* yB;
  float* meddenom;
  int* outp;
};

__device__ inline unsigned f2key(float f){
  unsigned b=__float_as_uint(f);
  return (b&0x80000000u)? ~b : (b|0x80000000u);
}
__device__ inline float key2f(unsigned k){
  unsigned b=(k&0x80000000u)? (k^0x80000000u) : ~k;
  return __uint_as_float(b);
}
__device__ inline unsigned long long shfl_xor_u64(unsigned long long v,int m){
  unsigned lo=(unsigned)v, hi=(unsigned)(v>>32);
  lo=__shfl_xor(lo,m,64); hi=__shfl_xor(hi,m,64);
  return (((unsigned long long)hi)<<32)|lo;
}

// ---------- setup: unique classes + support counts ----------
__global__ void k_init(P p){
  if (threadIdx.x==0){
    int labs[CMAX]; int cnt[CMAX]; int C=0;
    for (int s=0;s<p.S;s++){
      int l=p.ys[s]; int f=-1;
      for(int c=0;c<C;c++) if(labs[c]==l){f=c;break;}
      if(f<0){ if(C<CMAX){labs[C]=l;cnt[C]=1;C++;} }
      else cnt[f]++;
    }
    for(int a=0;a<C;a++)for(int b=a+1;b<C;b++)
      if(labs[b]<labs[a]){int t=labs[a];labs[a]=labs[b];labs[b]=t;
                          t=cnt[a];cnt[a]=cnt[b];cnt[b]=t;}
    for(int c=0;c<C;c++){p.cls[c]=labs[c];p.scount[c]=cnt[c];}
    p.meta[0]=C;
  }
}

// ---------- prototypes ----------
__global__ void k_proto(P p){
  int c=blockIdx.x; int C=p.meta[0];
  for(int d=threadIdx.x; d<p.D; d+=blockDim.x){
    float s=0.f;
    if(c<C){
      int lab=p.cls[c];
      for(int j=0;j<p.S;j++) if(p.ys[j]==lab) s+=p.fs[(size_t)j*p.D+d];
      s/= (float)p.scount[c];
    }
    p.proto[(size_t)c*p.D+d]=s;
  }
}

// ---------- Gram matrix over B = [feat_q ; prototypes], float4 inner ----------
__global__ void k_gram(P p){
  __shared__ float arow[1024];
  int a=blockIdx.x;
  const float* ra = (a<p.Q)? p.fq + (size_t)a*p.D : p.proto + (size_t)(a-p.Q)*p.D;
  const float* A = ra;
  if(p.D<=1024){
    for(int d=threadIdx.x; d<p.D; d+=blockDim.x) arow[d]=ra[d];
    __syncthreads();
    A=(const float*)arow;
  }
  int D4=p.D>>2; int Dt=D4<<2;
  for(int b=threadIdx.x; b<p.BN; b+=blockDim.x){
    const float* rb=(b<p.Q)? p.fq+(size_t)b*p.D : p.proto+(size_t)(b-p.Q)*p.D;
    const float4* a4=(const float4*)A;
    const float4* b4=(const float4*)rb;
    float s=0.f;
    #pragma unroll 4
    for(int d=0;d<D4;d++){
      float4 x=a4[d], y=b4[d];
      s += x.x*y.x + x.y*y.y + x.z*y.z + x.w*y.w;
    }
    for(int d=Dt;d<p.D;d++) s += A[d]*rb[d];
    p.G[(size_t)a*p.BN+b]=s;
  }
}

// ---------- cosine matrix of queries ----------
__global__ void k_cos(P p){
  int t=blockIdx.x*blockDim.x+threadIdx.x;
  if(t>=p.Q*p.Q)return;
  int i=t/p.Q, j=t%p.Q;
  p.cosq[t]=p.G[(size_t)i*p.BN+j]/(sqrtf(p.G[(size_t)i*p.BN+i])*sqrtf(p.G[(size_t)j*p.BN+j]));
}

// ---------- bootstrap labels ----------
__global__ void k_yboot(P p){
  int q=blockIdx.x*blockDim.x+threadIdx.x;
  if(q>=p.Q)return;
  int C=p.meta[0];
  float gq=p.G[(size_t)q*p.BN+q];
  float best=INFINITY; int bc=0;
  for(int c=0;c<C;c++){
    int pc=p.Q+c;
    float d2=gq+p.G[(size_t)pc*p.BN+pc]-2.f*p.G[(size_t)q*p.BN+pc];
    d2=fmaxf(d2,0.f);
    if(d2<best){best=d2;bc=c;}
  }
  p.ybt[q]=bc;
}

// ---------- per-class index lists + kq: wave-parallel ballot compaction ----------
__global__ void k_qidx(P p){
  int c=blockIdx.x; int C=p.meta[0];
  int lane=threadIdx.x;
  if(c>=C){ if(lane==0){p.qcount[c]=0;p.kq[c]=0;} return; }
  int base=0;
  for(int q0=0;q0<p.Q;q0+=64){
    int q=q0+lane;
    bool in = (q<p.Q) && (p.ybt[q]==c);
    unsigned long long mask=__ballot(in);
    int pre=__popcll(mask & ((lane==63)?0x7FFFFFFFFFFFFFFFull:((1ull<<lane)-1ull)));
    if(in) p.qidx[c*p.Q+base+pre]=q;
    base+=__popcll(mask);
  }
  if(lane==0) p.qcount[c]=base;
  int pc=p.Q+c;
  float gp=p.G[(size_t)pc*p.BN+pc];
  unsigned long long best=0xFFFFFFFFFFFFFFFFull;
  for(int t=lane;t<base;t+=64){
    int q=p.qidx[c*p.Q+t];
    float d2=fmaxf(p.G[(size_t)q*p.BN+q]+gp-2.f*p.G[(size_t)q*p.BN+pc],0.f);
    unsigned long long key=(((unsigned long long)f2key(d2))<<32)|(unsigned)t;
    if(key<best)best=key;
  }
  #pragma unroll
  for(int s=32;s>=1;s>>=1){
    unsigned long long o=shfl_xor_u64(best,s);
    if(o<best)best=o;
  }
  if(lane==0){
    int t=(int)(unsigned)(best&0xFFFFFFFFull);
    p.kq[c]=(base>0)? p.qidx[c*p.Q+t] : 0;
  }
}

// ---------- per-class median: gather keys once + 4-pass radix select ----------
__global__ void k_median(P p){
  __shared__ unsigned hist[256];
  __shared__ unsigned sPref; __shared__ int sTrem;
  __shared__ int sqidx[512];
  int c=blockIdx.x; int C=p.meta[0];
  int m=(c<C)? p.qcount[c]:0;
  int tid=threadIdx.x;
  if(m<2){ if(tid==0) p.thr[c]=INFINITY; return; }
  const int* qix;
  if(p.Q<=512){
    for(int t=tid;t<m;t+=blockDim.x) sqidx[t]=p.qidx[c*p.Q+t];
    __syncthreads();
    qix=sqidx;
  } else qix=p.qidx+c*p.Q;
  int total=m*m;
  unsigned* keys=p.cosk+(size_t)c*p.Q*p.Q;
  for(int t=tid;t<total;t+=blockDim.x){
    int a=t/m, b=t-a*m;
    keys[t]=f2key(p.cosq[(size_t)qix[a]*p.Q+qix[b]]);
  }
  if(tid==0){ sPref=0u; sTrem=(total-1)/2; }
  __syncthreads();
  unsigned prefmask=0u;
  for(int shift=24;shift>=0;shift-=8){
    hist[tid&255]=0u;
    __syncthreads();
    unsigned pref=sPref;
    for(int t=tid;t<total;t+=blockDim.x){
      unsigned key=keys[t];
      if((key&prefmask)==pref) atomicAdd(&hist[(key>>shift)&255],1u);
    }
    __syncthreads();
    if(tid==0){
      int trem=sTrem; unsigned cum=0;
      for(int b=0;b<256;b++){
        unsigned h=hist[b];
        if(cum+h>(unsigned)trem){ sPref=pref|((unsigned)b<<shift); sTrem=trem-(int)cum; break; }
        cum+=h;
      }
    }
    __syncthreads();
    prefmask|=(0xFFu<<shift);
  }
  if(tid==0) p.thr[c]=key2f(sPref);
}

// ---------- per-class pair row-counts + prefix ----------
__global__ void k_rowcnt(P p){
  int c=blockIdx.x; int C=p.meta[0];
  int m=(c<C)? p.qcount[c]:0;
  if(m<2){ if(threadIdx.x==0) p.paircnt[c]=0; return; }
  float th=p.thr[c];
  for(int a=threadIdx.x;a<m;a+=blockDim.x){
    int ia=p.qidx[c*p.Q+a]; int cnt=0;
    const float* row=p.cosq+(size_t)ia*p.Q;
    for(int b=a+1;b<m;b++){
      int ib=p.qidx[c*p.Q+b];
      cnt += (row[ib]>=th);
    }
    p.rowcnt[c*p.Q+a]=cnt;
  }
  __syncthreads();
  if(threadIdx.x==0){
    int run=0;
    for(int a=0;a<m;a++){p.rowoff[c*p.Q+a]=run; run+=p.rowcnt[c*p.Q+a];}
    p.paircnt[c]=run;
  }
}

// ---------- bases, n, k + iteration-state init ----------
__global__ void k_bases(P p){
  int C=p.meta[0]; int cur=p.Q;
  for(int c=0;c<C;c++){
    p.basev[c]=cur;
    if(p.qcount[c]>=2) cur += p.paircnt[c]+1;
  }
  int n=cur; if(n>p.NMAX)n=p.NMAX;
  p.meta[1]=n;
  int k=31-__clz(n); if(k<1)k=1; if(k>KMAX-1)k=KMAX-1;
  p.meta[2]=k;
  p.meta[3]=0;   // done
  p.meta[4]=0;   // parity (cur buffer index)
  p.meta[5]=0;   // block counter
  for(int t=0;t<64;t++) p.gmaxu[t]=0u;
}

// ---------- uv for query rows + zero indeg ----------
__global__ void k_uv(P p){
  int r=blockIdx.x*blockDim.x+threadIdx.x;
  if(r>=p.NMAX)return;
  p.indeg[r]=0;
  if(r<p.Q){ p.uv[2*r]=r; p.uv[2*r+1]=r; }
}

// ---------- uv for virtual rows ----------
__global__ void k_uvpairs(P p){
  int c=blockIdx.x; int C=p.meta[0];
  int m=(c<C)? p.qcount[c]:0;
  if(m<2)return;
  float th=p.thr[c];
  int bs=p.basev[c];
  for(int a=threadIdx.x;a<m;a+=blockDim.x){
    int ia=p.qidx[c*p.Q+a];
    int off=bs+p.rowoff[c*p.Q+a]; int cnt=0;
    const float* row=p.cosq+(size_t)ia*p.Q;
    for(int b=a+1;b<m;b++){
      int ib=p.qidx[c*p.Q+b];
      if(row[ib]>=th){
        int r=off+cnt;
        p.uv[2*r]=ia; p.uv[2*r+1]=ib;
        cnt++;
      }
    }
  }
  if(threadIdx.x==0){
    int r=bs+p.paircnt[c];
    p.uv[2*r]=p.Q+c; p.uv[2*r+1]=p.kq[c];
  }
}

// ---------- per-row norm^2 from Gram ----------
__global__ void k_rn2(P p){
  int r=blockIdx.x*blockDim.x+threadIdx.x;
  int n=p.meta[1]; if(r>=n)return;
  int u=p.uv[2*r],v=p.uv[2*r+1];
  p.rn2[r]=0.25f*(p.G[(size_t)u*p.BN+u]+2.f*p.G[(size_t)u*p.BN+v]+p.G[(size_t)v*p.BN+v]);
}

// ---------- kNN: 1 wave per row, register top-16 via u64 keys ----------
__global__ void k_knn(P p){
  __shared__ float sGu[BNMAX];
  __shared__ float sGv[BNMAX];
  int i=blockIdx.x;
  int n=p.meta[1]; if(i>=n)return;
  int kp1=p.meta[2]+1;
  int lane=threadIdx.x;
  int u1=p.uv[2*i], v1=p.uv[2*i+1];
  const float* Gu=p.G+(size_t)u1*p.BN;
  const float* Gv=p.G+(size_t)v1*p.BN;
  const float* bu=Gu; const float* bv=Gv;
  if(p.BN<=BNMAX){
    for(int d=lane; d<p.BN; d+=64){ sGu[d]=Gu[d]; sGv[d]=Gv[d]; }
    __syncthreads();
    bu=(const float*)sGu; bv=(const float*)sGv;
  }
  float rni=p.rn2[i];
  unsigned long long r[16];
  #pragma unroll
  for(int t=0;t<16;t++) r[t]=0xFFFFFFFFFFFFFFFFull;
  for(int j=lane;j<n;j+=64){
    int2 w=((const int2*)p.uv)[j];
    float dot=0.25f*(bu[w.x]+bu[w.y]+bv[w.x]+bv[w.y]);
    float d2=fmaxf(rni+p.rn2[j]-2.f*dot,0.f);
    unsigned long long key=(((unsigned long long)f2key(d2))<<32)|(unsigned)j;
    if(key<r[15]){
      #pragma unroll
      for(int t=0;t<16;t++){
        unsigned long long lo=key<r[t]?key:r[t];
        unsigned long long hi=key<r[t]?r[t]:key;
        r[t]=lo; key=hi;
      }
    }
  }
  for(int t=0;t<kp1;t++){
    unsigned long long m=r[0];
    #pragma unroll
    for(int s=32;s>=1;s>>=1){
      unsigned long long o=shfl_xor_u64(m,s);
      if(o<m)m=o;
    }
    if(r[0]==m){
      #pragma unroll
      for(int q=0;q<15;q++) r[q]=r[q+1];
      r[15]=0xFFFFFFFFFFFFFFFFull;
    }
    if(lane==0){
      int j=(int)(unsigned)(m&0xFFFFFFFFull);
      float d2=key2f((unsigned)(m>>32));
      float dd=sqrtf(fmaxf(d2,1e-30f));
      if(t>=1){ p.nbrs[(size_t)i*KMAX+t-1]=j; p.dnb[(size_t)i*KMAX+t-1]=dd; }
      if(t==kp1-1) p.sigma[i]=dd+1e-8f;
    }
  }
}

// ---------- edge weights + in-degree count (merged) ----------
__global__ void k_wgtcnt(P p){
  int i=blockIdx.x*blockDim.x+threadIdx.x;
  int n=p.meta[1]; if(i>=n)return;
  int k=p.meta[2];
  float si=p.sigma[i];
  for(int q=0;q<k;q++){
    int j=p.nbrs[(size_t)i*KMAX+q];
    p.wgt[(size_t)i*KMAX+q]=expf(-p.dnb[(size_t)i*KMAX+q]/(si*p.sigma[j]));
    atomicAdd(&p.indeg[j],1);
  }
}

// ---------- exclusive scan of indeg ----------
__global__ void k_scan(P p){
  __shared__ int part[TPB];
  int n=p.meta[1];
  int chunk=(n+TPB-1)/TPB;
  int beg=threadIdx.x*chunk, end=beg+chunk; if(end>n)end=n;
  int s=0;
  for(int i=beg;i<end;i++) s+=p.indeg[i];
  part[threadIdx.x]=s; __syncthreads();
  if(threadIdx.x==0){
    int run=0;
    for(int t=0;t<TPB;t++){int v=part[t];part[t]=run;run+=v;}
    p.inoff[n]=run;
  }
  __syncthreads();
  int run=part[threadIdx.x];
  for(int i=beg;i<end;i++){
    p.inoff[i]=run; p.cursor[i]=run; run+=p.indeg[i];
  }
}

// ---------- fill transpose edges (unsorted, atomic slots) ----------
__global__ void k_fill(P p){
  int i=blockIdx.x*blockDim.x+threadIdx.x;
  int n=p.meta[1]; if(i>=n)return;
  int k=p.meta[2];
  for(int q=0;q<k;q++){
    int dst=p.nbrs[(size_t)i*KMAX+q];
    int slot=atomicAdd(&p.cursor[dst],1);
    p.insrcU[slot]=i; p.inwU[slot]=p.wgt[(size_t)i*KMAX+q]; p.indst[slot]=dst;
  }
}

// ---------- deterministic order: thread-per-edge rank-by-count ----------
__global__ void k_rank(P p){
  int e=blockIdx.x*blockDim.x+threadIdx.x;
  int n=p.meta[1];
  int E=p.inoff[n];
  if(e>=E)return;
  int dst=p.indst[e];
  int b=p.inoff[dst], en=p.inoff[dst+1];
  int s=p.insrcU[e]; float w=p.inwU[e];
  int rank=0;
  for(int x=b;x<en;x++) rank += (p.insrcU[x]<s);
  p.insrc[b+rank]=s; p.inw[b+rank]=w;
}

// ---------- D_inv, a-matrix (+INF padding), d_min ----------
__global__ void k_dad(P p){
  int i=blockIdx.x*blockDim.x+threadIdx.x;
  int n=p.meta[1]; if(i>=n)return;
  int k=p.meta[2]; int C=p.meta[0];
  float s=0.f;
  for(int q=0;q<k;q++) s+=p.wgt[(size_t)i*KMAX+q];
  for(int e=p.inoff[i];e<p.inoff[i+1];e++) s+=p.inw[e];
  p.dinv[i]=1.f/(0.5f*s+1e-8f);
  int u=p.uv[2*i],v=p.uv[2*i+1];
  float rn=p.rn2[i]; float mn=INFINITY;
  #pragma unroll
  for(int c=0;c<CMAX;c++){
    float a=INFINITY;
    if(c<C){
      int pc=p.Q+c;
      a=rn+p.G[(size_t)pc*p.BN+pc]-(p.G[(size_t)u*p.BN+pc]+p.G[(size_t)v*p.BN+pc]);
      a=fmaxf(a,0.f);
      mn=fminf(mn,a);
    }
    p.amat[(size_t)i*CMAX+c]=a;
  }
  p.dmin[i]=sqrtf(fmaxf(mn,1e-30f));
}

// ---------- median of d: 4-pass radix select ----------
__global__ void k_medd(P p){
  __shared__ unsigned hist[256];
  __shared__ unsigned sPref; __shared__ int sTrem;
  int n=p.meta[1];
  int tid=threadIdx.x;
  if(tid==0){ sPref=0u; sTrem=(n-1)/2; }
  __syncthreads();
  unsigned prefmask=0u;
  for(int shift=24;shift>=0;shift-=8){
    hist[tid&255]=0u;
    __syncthreads();
    unsigned pref=sPref;
    for(int i=tid;i<n;i+=blockDim.x){
      unsigned key=f2key(p.dmin[i]);
      if((key&prefmask)==pref) atomicAdd(&hist[(key>>shift)&255],1u);
    }
    __syncthreads();
    if(tid==0){
      int trem=sTrem; unsigned cum=0;
      for(int b=0;b<256;b++){
        unsigned h=hist[b];
        if(cum+h>(unsigned)trem){ sPref=pref|((unsigned)b<<shift); sTrem=trem-(int)cum; break; }
        cum+=h;
      }
    }
    __syncthreads();
    prefmask|=(0xFFu<<shift);
  }
  if(tid==0){
    float med=key2f(sPref);
    p.meddenom[0]=2.f*med*med+1e-8f;
  }
}

// ---------- lambda, scale, y0 (full 8-wide, INF-padded amat) ----------
__global__ void k_y0(P p){
  int i=blockIdx.x*blockDim.x+threadIdx.x;
  int n=p.meta[1]; if(i>=n)return;
  float la=expf(-(p.dmin[i]*p.dmin[i])/p.meddenom[0]);
  p.scalev[i]=la*p.dinv[i];
  float mn=INFINITY;
  #pragma unroll
  for(int c=0;c<CMAX;c++) mn=fminf(mn,p.amat[(size_t)i*CMAX+c]);
  float ex[CMAX]; float sum=0.f;
  #pragma unroll
  for(int c=0;c<CMAX;c++){
    float e=expf(mn-p.amat[(size_t)i*CMAX+c]);   // INF -> 0
    ex[c]=e; sum+=e;
  }
  float inv=1.f/sum;
  #pragma unroll
  for(int c=0;c<CMAX;c++) p.yA[(size_t)i*CMAX+c]=ex[c]*inv;
}

// ---------- one propagation step, multi-block; freeze via device state ----------
__global__ void k_step(P p,int t){
  if(p.meta[3]) return;                 // converged earlier: y frozen
  int n=p.meta[1]; int k=p.meta[2];
  int par=p.meta[4];
  float* cur=par? p.yB : p.yA;
  float* nxt=par? p.yA : p.yB;
  int i=blockIdx.x*blockDim.x+threadIdx.x;
  float dmx=0.f;
  if(i<n){
    float4 wa=make_float4(0.f,0.f,0.f,0.f), wb=make_float4(0.f,0.f,0.f,0.f);
    #pragma unroll 4
    for(int q=0;q<k;q++){
      int j=p.nbrs[(size_t)i*KMAX+q];
      float w=p.wgt[(size_t)i*KMAX+q];
      const float4* yr=(const float4*)(cur+(size_t)j*CMAX);
      float4 y0=yr[0],y1=yr[1];
      wa.x+=w*y0.x; wa.y+=w*y0.y; wa.z+=w*y0.z; wa.w+=w*y0.w;
      wb.x+=w*y1.x; wb.y+=w*y1.y; wb.z+=w*y1.z; wb.w+=w*y1.w;
    }
    int e1=p.inoff[i+1];
    for(int e=p.inoff[i];e<e1;e++){
      int j=p.insrc[e]; float w=p.inw[e];
      const float4* yr=(const float4*)(cur+(size_t)j*CMAX);
      float4 y0=yr[0],y1=yr[1];
      wa.x+=w*y0.x; wa.y+=w*y0.y; wa.z+=w*y0.z; wa.w+=w*y0.w;
      wb.x+=w*y1.x; wb.y+=w*y1.y; wb.z+=w*y1.z; wb.w+=w*y1.w;
    }
    float sc=p.scalev[i]*0.5f;
    const float4* am=(const float4*)(p.amat+(size_t)i*CMAX);
    float4 a0=am[0],a1=am[1];
    float l0=sc*wa.x-a0.x, l1=sc*wa.y-a0.y, l2=sc*wa.z-a0.z, l3=sc*wa.w-a0.w;
    float l4=sc*wb.x-a1.x, l5=sc*wb.y-a1.y, l6=sc*wb.z-a1.z, l7=sc*wb.w-a1.w;
    float mx=fmaxf(fmaxf(fmaxf(l0,l1),fmaxf(l2,l3)),fmaxf(fmaxf(l4,l5),fmaxf(l6,l7)));
    float e0=expf(l0-mx),e1f=expf(l1-mx),e2=expf(l2-mx),e3=expf(l3-mx);
    float e4=expf(l4-mx),e5=expf(l5-mx),e6=expf(l6-mx),e7=expf(l7-mx);
    float inv=1.f/(e0+e1f+e2+e3+e4+e5+e6+e7);
    float4 o0=make_float4(e0*inv,e1f*inv,e2*inv,e3*inv);
    float4 o1=make_float4(e4*inv,e5*inv,e6*inv,e7*inv);
    const float4* cr=(const float4*)(cur+(size_t)i*CMAX);
    float4 c0=cr[0],c1=cr[1];
    dmx=fmaxf(dmx,fabsf(o0.x-c0.x)); dmx=fmaxf(dmx,fabsf(o0.y-c0.y));
    dmx=fmaxf(dmx,fabsf(o0.z-c0.z)); dmx=fmaxf(dmx,fabsf(o0.w-c0.w));
    dmx=fmaxf(dmx,fabsf(o1.x-c1.x)); dmx=fmaxf(dmx,fabsf(o1.y-c1.y));
    dmx=fmaxf(dmx,fabsf(o1.z-c1.z)); dmx=fmaxf(dmx,fabsf(o1.w-c1.w));
    float4* nr=(float4*)(nxt+(size_t)i*CMAX);
    nr[0]=o0; nr[1]=o1;
  }
  #pragma unroll
  for(int s=32;s>=1;s>>=1) dmx=fmaxf(dmx,__shfl_xor(dmx,s,64));
  if(threadIdx.x==0){
    atomicMax(p.gmaxu+t,__float_as_uint(dmx));   // dmx>=0 -> bits monotone
    __threadfence();
    int fin=atomicAdd(&p.meta[5],1);
    if(fin==(int)gridDim.x-1){                   // last block: commit decision
      p.meta[5]=0;
      float mm=__uint_as_float(p.gmaxu[t]);
      if(mm<1e-4f) p.meta[3]=1;                  // freeze: keep old parity
      else         p.meta[4]=par^1;              // advance
    }
  }
}

// ---------- final argmax over query rows ----------
__global__ void k_arg(P p){
  int q=blockIdx.x*blockDim.x+threadIdx.x;
  if(q>=p.Q)return;
  int C=p.meta[0];
  const float* cur=p.meta[4]? p.yB : p.yA;
  float best=cur[(size_t)q*CMAX+0]; int bc=0;
  for(int c=1;c<C;c++){
    float v=cur[(size_t)q*CMAX+c];
    if(v>best){best=v;bc=c;}
  }
  p.outp[q]=bc;
}

// =======================================================================

static void make_layout(char* base,int S,int Q,int D,int BN,long N,
                        const float*fs,const int*ys,const float*fq,
                        int* outp, P* pp, size_t* need){
  size_t off=0;
  auto A=[&](size_t b)->char*{
    size_t o=(off+255)&~(size_t)255; off=o+b; return base+o;
  };
  P p{};
  p.fs=fs;p.ys=ys;p.fq=fq;p.S=S;p.Q=Q;p.D=D;p.BN=BN;p.NMAX=(int)N;
  p.proto=(float*)A(4ul*CMAX*D);
  p.G=(float*)A(4ul*(size_t)BN*BN);
  p.cosq=(float*)A(4ul*(size_t)Q*Q);
  p.ybt=(int*)A(4ul*Q);
  p.cls=(int*)A(4ul*CMAX);
  p.scount=(int*)A(4ul*CMAX);
  p.qcount=(int*)A(4ul*CMAX);
  p.qidx=(int*)A(4ul*CMAX*Q);
  p.kq=(int*)A(4ul*CMAX);
  p.thr=(float*)A(4ul*CMAX);
  p.rowcnt=(int*)A(4ul*CMAX*Q);
  p.rowoff=(int*)A(4ul*CMAX*Q);
  p.paircnt=(int*)A(4ul*CMAX);
  p.basev=(int*)A(4ul*CMAX);
  p.meta=(int*)A(4ul*16);
  p.uv=(int*)A(8ul*N);
  p.rn2=(float*)A(4ul*N);
  p.nbrs=(int*)A(4ul*KMAX*N);
  p.dnb=(float*)A(4ul*KMAX*N);
  p.wgt=(float*)A(4ul*KMAX*N);
  p.sigma=(float*)A(4ul*N);
  p.indeg=(int*)A(4ul*N);
  p.inoff=(int*)A(4ul*(N+1));
  p.cursor=(int*)A(4ul*N);
  p.insrcU=(int*)A(4ul*KMAX*N);
  p.inwU=(float*)A(4ul*KMAX*N);
  p.indst=(int*)A(4ul*KMAX*N);
  p.insrc=(int*)A(4ul*KMAX*N);
  p.inw=(float*)A(4ul*KMAX*N);
  p.cosk=(unsigned*)A(4ul*CMAX*(size_t)Q*Q);
  p.gmaxu=(unsigned*)A(4ul*64);
  p.amat=(float*)A(4ul*CMAX*N);
  p.dinv=(float*)A(4ul*N);
  p.dmin=(float*)A(4ul*N);
  p.scalev=(float*)A(4ul*N);
  p.yA=(float*)A(4ul*CMAX*N);
  p.yB=(float*)A(4ul*CMAX*N);
  p.meddenom=(float*)A(4ul*4);
  p.outp=outp;
  *pp=p; *need=off;
}

extern "C" void kernel_launch(void* const* d_in, const int* in_sizes, int n_in,
                              void* d_out, int out_size, void* d_ws, size_t ws_size,
                              hipStream_t stream){
  const float* fs=(const float*)d_in[0];
  const int*   ys=(const int*)d_in[1];
  const float* fq=(const float*)d_in[2];
  int S=in_sizes[1];
  int D=in_sizes[0]/S;
  int Q=in_sizes[2]/D;
  int BN=Q+CMAX;

  long full=(long)Q + (long)Q*(Q-1)/2 + CMAX;   // absolute worst-case n
  long cand[4]={full,16384,8192,5000};
  P p{}; size_t need=0; int NMAX=(int)cand[3];
  for(int ci=0;ci<4;ci++){
    long N=cand[ci]; if(N<Q+CMAX)N=Q+CMAX;
    make_layout((char*)d_ws,S,Q,D,BN,N,fs,ys,fq,(int*)d_out,&p,&need);
    NMAX=(int)N;
    if(need<=ws_size) break;
  }

  int gN=(NMAX+TPB-1)/TPB;
  long gEl=((long)NMAX*KMAX+TPB-1)/TPB;
  int gE=(int)gEl;
  int gS=(NMAX+63)/64;

  k_init   <<<1, 64, 0, stream>>>(p);
  k_proto  <<<CMAX, TPB, 0, stream>>>(p);
  k_gram   <<<BN, TPB, 0, stream>>>(p);
  k_cos    <<<(Q*Q+TPB-1)/TPB, TPB, 0, stream>>>(p);
  k_yboot  <<<(Q+TPB-1)/TPB, TPB, 0, stream>>>(p);
  k_qidx   <<<CMAX, 64, 0, stream>>>(p);
  k_median <<<CMAX, TPB, 0, stream>>>(p);
  k_rowcnt <<<CMAX, TPB, 0, stream>>>(p);
  k_bases  <<<1, 1, 0, stream>>>(p);
  k_uv     <<<gN, TPB, 0, stream>>>(p);
  k_uvpairs<<<CMAX, TPB, 0, stream>>>(p);
  k_rn2    <<<gN, TPB, 0, stream>>>(p);
  k_knn    <<<NMAX, 64, 0, stream>>>(p);
  k_wgtcnt <<<gN, TPB, 0, stream>>>(p);
  k_scan   <<<1, TPB, 0, stream>>>(p);
  k_fill   <<<gN, TPB, 0, stream>>>(p);
  k_rank   <<<gE, TPB, 0, stream>>>(p);
  k_dad    <<<gN, TPB, 0, stream>>>(p);
  k_medd   <<<1, TPB, 0, stream>>>(p);
  k_y0     <<<gN, TPB, 0, stream>>>(p);
  for(int t=0;t<50;t++)
    k_step <<<gS, 64, 0, stream>>>(p, t);
  k_arg    <<<(Q+TPB-1)/TPB, TPB, 0, stream>>>(p);
}